// Round 7
// baseline (1101.356 us; speedup 1.0000x reference)
//
#include <hip/hip_runtime.h>
#include <hip/hip_fp16.h>

#define NN 100000
#define NE 2500000
#define RANGE 64
#define RSHIFT 6
#define RMASK 63
#define NBUCK 1563                      // ceil(NN/64)
#define CHUNK 8192
#define NBLK_A ((NE + CHUNK - 1) / CHUNK)   // 306

__device__ __forceinline__ float relu_(float x){ return fmaxf(x, 0.f); }

// h16[n,0:32] = relu(nf[n,0:2] @ W_in + b_in)  (fp16 master)
__global__ __launch_bounds__(256) void k_node_embed16(
    const float* __restrict__ nf, const float* __restrict__ Win,
    const float* __restrict__ bin, __half* __restrict__ h16)
{
  int n = blockIdx.x * 256 + threadIdx.x;
  if (n >= NN) return;
  float f0 = nf[2*n], f1 = nf[2*n+1];
  const float4* W0 = (const float4*)Win;
  const float4* W1 = (const float4*)(Win + 32);
  const float4* B  = (const float4*)bin;
  __half2* g2 = (__half2*)(h16 + (size_t)n * 32);
#pragma unroll
  for (int j = 0; j < 8; ++j) {
    float4 w0 = W0[j], w1 = W1[j], b = B[j], r;
    r.x = relu_(fmaf(f0, w0.x, fmaf(f1, w1.x, b.x)));
    r.y = relu_(fmaf(f0, w0.y, fmaf(f1, w1.y, b.y)));
    r.z = relu_(fmaf(f0, w0.z, fmaf(f1, w1.z, b.z)));
    r.w = relu_(fmaf(f0, w0.w, fmaf(f1, w1.w, b.w)));
    g2[2*j]   = __floats2half2_rn(r.x, r.y);
    g2[2*j+1] = __floats2half2_rn(r.z, r.w);
  }
}

// ---- bucket grouping (single partition pass; no within-bucket sort needed) ----

// per-block bucket histogram -> blockhist[block][bucket]; totals -> btot
__global__ __launch_bounds__(512) void k_histA(const int* __restrict__ row,
                                               int* __restrict__ btot,
                                               int* __restrict__ blockhist)
{
  __shared__ int hist[NBUCK];
  int t = threadIdx.x;
  for (int i = t; i < NBUCK; i += 512) hist[i] = 0;
  __syncthreads();
  int e0 = blockIdx.x * CHUNK + t;
#pragma unroll
  for (int k = 0; k < CHUNK / 512; ++k) {
    int e = e0 + k * 512;
    if (e < NE) atomicAdd(&hist[row[e] >> RSHIFT], 1);
  }
  __syncthreads();
  int* outp = blockhist + (size_t)blockIdx.x * NBUCK;
  for (int i = t; i < NBUCK; i += 512) {
    int c = hist[i];
    outp[i] = c;
    if (c) atomicAdd(&btot[i], c);
  }
}

// exclusive scan of NBUCK (<2048) bucket totals, 2 elems/thread
__global__ __launch_bounds__(1024) void k_scanA(const int* __restrict__ btot,
                                                int* __restrict__ bbase)
{
  __shared__ int s[1024];
  int t = threadIdx.x;
  int i0 = 2 * t, i1 = 2 * t + 1;
  int a = (i0 < NBUCK) ? btot[i0] : 0;
  int b = (i1 < NBUCK) ? btot[i1] : 0;
  int ps = a + b;
  s[t] = ps;
  __syncthreads();
  for (int off = 1; off < 1024; off <<= 1) {
    int v = (t >= off) ? s[t - off] : 0;
    __syncthreads();
    s[t] += v;
    __syncthreads();
  }
  int ex = s[t] - ps;
  if (i0 < NBUCK) bbase[i0] = ex;
  if (i1 < NBUCK) bbase[i1] = ex + a;
  if (t == 0) bbase[NBUCK] = NE;
}

// per-bucket scan across blocks: blockhist[b][i] -> global base offsets
__global__ __launch_bounds__(512) void k_colscan(int* __restrict__ blockhist,
                                                 const int* __restrict__ bbase)
{
  __shared__ int s[512];
  int i = blockIdx.x, t = threadIdx.x;
  int my = (t < NBLK_A) ? blockhist[(size_t)t * NBUCK + i] : 0;
  s[t] = my;
  __syncthreads();
  for (int off = 1; off < 512; off <<= 1) {
    int v = (t >= off) ? s[t - off] : 0;
    __syncthreads();
    s[t] += v;
    __syncthreads();
  }
  if (t < NBLK_A) blockhist[(size_t)t * NBUCK + i] = bbase[i] + s[t] - my;
}

// single pass: scatter packed keys (col<<6)|(row&63) bucket-contiguously
__global__ __launch_bounds__(512) void k_partition(
    const int* __restrict__ row, const int* __restrict__ col,
    const int* __restrict__ blockhist, unsigned int* __restrict__ keys)
{
  __shared__ int cur[NBUCK];
  __shared__ int base[NBUCK];
  int t = threadIdx.x, b = blockIdx.x;
  const int* bp = blockhist + (size_t)b * NBUCK;
  for (int i = t; i < NBUCK; i += 512) {
    base[i] = bp[i];
    cur[i] = 0;
  }
  __syncthreads();
  int e0 = b * CHUNK + t;
#pragma unroll
  for (int k = 0; k < CHUNK / 512; ++k) {
    int e = e0 + k * 512;
    if (e < NE) {
      int r = row[e];
      int bi = r >> RSHIFT;
      int idx = atomicAdd(&cur[bi], 1);
      keys[base[bi] + idx] = ((unsigned)col[e] << RSHIFT) | (unsigned)(r & RMASK);
    }
  }
}

// ---- per-bucket aggregation: LDS accumulate, then agg[n,:] = sum/deg ----
__global__ __launch_bounds__(256) void k_bucket_agg(
    const int* __restrict__ bbase, const unsigned int* __restrict__ keys,
    const __half* __restrict__ h16, float* __restrict__ agg)
{
  __shared__ float aggl[RANGE][33];
  __shared__ int cnt[RANGE];
  int t = threadIdx.x, b = blockIdx.x;
  for (int i = t; i < RANGE * 33; i += 256) ((float*)aggl)[i] = 0.f;
  if (t < RANGE) cnt[t] = 0;
  __syncthreads();
  int s0 = bbase[b], e1 = bbase[b + 1];
  int q = t & 3;
  const uint4* hv = (const uint4*)h16;
  for (int i = s0 + (t >> 2); i < e1; i += 64) {
    unsigned key = keys[i];
    int rl = (int)(key & RMASK);
    int c  = (int)(key >> RSHIFT);
    uint4 x = hv[c * 4 + q];
    const __half2* hp = (const __half2*)&x;
    float* dst = &aggl[rl][q * 8];
#pragma unroll
    for (int k = 0; k < 4; ++k) {
      float2 f = __half22float2(hp[k]);
      atomicAdd(dst + 2*k,     f.x);
      atomicAdd(dst + 2*k + 1, f.y);
    }
    if (q == 0) atomicAdd(&cnt[rl], 1);
  }
  __syncthreads();
  int nb = b * RANGE;
  for (int idx = t; idx < RANGE * 8; idx += 256) {
    int node = idx >> 3, qq = idx & 7;
    int n = nb + node;
    if (n >= NN) continue;
    float dinv = 1.0f / fmaxf((float)cnt[node], 1.0f);
    float4 r;
    r.x = aggl[node][qq*4+0] * dinv;
    r.y = aggl[node][qq*4+1] * dinv;
    r.z = aggl[node][qq*4+2] * dinv;
    r.w = aggl[node][qq*4+3] * dinv;
    ((float4*)agg)[(size_t)n * 8 + qq] = r;
  }
}

// layer-1 update: h16out = relu(concat(h16in, agg) @ W + b)
__global__ __launch_bounds__(256) void k_update(
    const __half* __restrict__ h16in, const float* __restrict__ agg,
    const float* __restrict__ W, const float* __restrict__ b,
    __half* __restrict__ h16out)
{
  __shared__ float Ws[2048];
  __shared__ float bs[32];
  int t = threadIdx.x;
  for (int i = t; i < 2048; i += 256) Ws[i] = W[i];
  if (t < 32) bs[t] = b[t];
  __syncthreads();
  int n = blockIdx.x * 256 + t;
  if (n >= NN) return;

  float x[64];
  const uint4* hv = (const uint4*)(h16in + (size_t)n * 32);
  const float4* a4 = (const float4*)(agg + (size_t)n * 32);
#pragma unroll
  for (int j = 0; j < 4; ++j) {
    uint4 hx = hv[j];
    const __half2* hp = (const __half2*)&hx;
#pragma unroll
    for (int k = 0; k < 4; ++k) {
      float2 f = __half22float2(hp[k]);
      x[j*8 + 2*k]     = f.x;
      x[j*8 + 2*k + 1] = f.y;
    }
  }
#pragma unroll
  for (int j = 0; j < 8; ++j) {
    float4 tv = a4[j];
    x[32+4*j+0] = tv.x; x[32+4*j+1] = tv.y;
    x[32+4*j+2] = tv.z; x[32+4*j+3] = tv.w;
  }
  float acc[32];
#pragma unroll
  for (int j = 0; j < 32; ++j) acc[j] = bs[j];
#pragma unroll
  for (int k = 0; k < 64; ++k) {
    float xk = x[k];
    const float* wr = Ws + k * 32;
#pragma unroll
    for (int j = 0; j < 32; ++j) acc[j] = fmaf(xk, wr[j], acc[j]);
  }
  __half2* g2 = (__half2*)(h16out + (size_t)n * 32);
#pragma unroll
  for (int j = 0; j < 16; ++j)
    g2[j] = __floats2half2_rn(relu_(acc[2*j]), relu_(acc[2*j+1]));
}

// layer-2 update fused with edge projection: u = h2@We1[0:32]+be1, v = h2@We1[32:64]
__global__ __launch_bounds__(256) void k_update2_uv(
    const __half* __restrict__ h16in, const float* __restrict__ agg,
    const float* __restrict__ W, const float* __restrict__ b,
    const float* __restrict__ We1, const float* __restrict__ be1,
    __half* __restrict__ u, __half* __restrict__ v)
{
  __shared__ float Ws[2048];
  __shared__ float Es[2048];
  __shared__ float bs[32];
  __shared__ float bes[32];
  int t = threadIdx.x;
  for (int i = t; i < 2048; i += 256) { Ws[i] = W[i]; Es[i] = We1[i]; }
  if (t < 32) { bs[t] = b[t]; bes[t] = be1[t]; }
  __syncthreads();
  int n = blockIdx.x * 256 + t;
  if (n >= NN) return;

  float x[64];
  const uint4* hv = (const uint4*)(h16in + (size_t)n * 32);
  const float4* a4 = (const float4*)(agg + (size_t)n * 32);
#pragma unroll
  for (int j = 0; j < 4; ++j) {
    uint4 hx = hv[j];
    const __half2* hp = (const __half2*)&hx;
#pragma unroll
    for (int k = 0; k < 4; ++k) {
      float2 f = __half22float2(hp[k]);
      x[j*8 + 2*k]     = f.x;
      x[j*8 + 2*k + 1] = f.y;
    }
  }
#pragma unroll
  for (int j = 0; j < 8; ++j) {
    float4 tv = a4[j];
    x[32+4*j+0] = tv.x; x[32+4*j+1] = tv.y;
    x[32+4*j+2] = tv.z; x[32+4*j+3] = tv.w;
  }
  float h2[32];
#pragma unroll
  for (int j = 0; j < 32; ++j) h2[j] = bs[j];
#pragma unroll
  for (int k = 0; k < 64; ++k) {
    float xk = x[k];
    const float* wr = Ws + k * 32;
#pragma unroll
    for (int j = 0; j < 32; ++j) h2[j] = fmaf(xk, wr[j], h2[j]);
  }
#pragma unroll
  for (int j = 0; j < 32; ++j) h2[j] = relu_(h2[j]);

  float au[32], av[32];
#pragma unroll
  for (int j = 0; j < 32; ++j) { au[j] = bes[j]; av[j] = 0.f; }
#pragma unroll
  for (int k = 0; k < 32; ++k) {
    float hk = h2[k];
    const float* wu = Es + k * 32;
    const float* wv = Es + (32 + k) * 32;
#pragma unroll
    for (int j = 0; j < 32; ++j) {
      au[j] = fmaf(hk, wu[j], au[j]);
      av[j] = fmaf(hk, wv[j], av[j]);
    }
  }
  __half2* u2 = (__half2*)(u + (size_t)n * 32);
  __half2* v2 = (__half2*)(v + (size_t)n * 32);
#pragma unroll
  for (int j = 0; j < 16; ++j) {
    u2[j] = __floats2half2_rn(au[2*j], au[2*j+1]);
    v2[j] = __floats2half2_rn(av[2*j], av[2*j+1]);
  }
}

// flux[e] = relu(u[row]+v[col]).We2 + be2   (4 lanes/edge, uint4 fp16 loads)
__global__ __launch_bounds__(256) void k_flux(
    const int* __restrict__ row, const int* __restrict__ col,
    const __half* __restrict__ u, const __half* __restrict__ v,
    const float* __restrict__ We2, const float* __restrict__ be2,
    float* __restrict__ out)
{
  int gid = blockIdx.x * 256 + threadIdx.x;
  int e = gid >> 2, q = gid & 3;
  if (e >= NE) return;
  int r = row[e], c = col[e];
  uint4 ua = ((const uint4*)u)[r * 4 + q];   // 8 halfs
  uint4 vb = ((const uint4*)v)[c * 4 + q];
  const __half2* ah = (const __half2*)&ua;
  const __half2* bh = (const __half2*)&vb;
  const float4* w4 = (const float4*)(We2 + q * 8);
  float4 w0 = w4[0], w1 = w4[1];
  float p = 0.f;
  {
    float2 a = __half22float2(ah[0]), b = __half22float2(bh[0]);
    p += relu_(a.x + b.x) * w0.x + relu_(a.y + b.y) * w0.y;
    a = __half22float2(ah[1]); b = __half22float2(bh[1]);
    p += relu_(a.x + b.x) * w0.z + relu_(a.y + b.y) * w0.w;
    a = __half22float2(ah[2]); b = __half22float2(bh[2]);
    p += relu_(a.x + b.x) * w1.x + relu_(a.y + b.y) * w1.y;
    a = __half22float2(ah[3]); b = __half22float2(bh[3]);
    p += relu_(a.x + b.x) * w1.z + relu_(a.y + b.y) * w1.w;
  }
  p += __shfl_xor(p, 1, 4);
  p += __shfl_xor(p, 2, 4);
  if (q == 0) out[e] = p + be2[0];
}

extern "C" void kernel_launch(void* const* d_in, const int* in_sizes, int n_in,
                              void* d_out, int out_size, void* d_ws, size_t ws_size,
                              hipStream_t stream) {
  const float* nf   = (const float*)d_in[0];
  const int*   ei   = (const int*)d_in[1];
  const float* Win  = (const float*)d_in[2];
  const float* bin  = (const float*)d_in[3];
  const float* Wupd = (const float*)d_in[4];
  const float* bupd = (const float*)d_in[5];
  const float* We1  = (const float*)d_in[6];
  const float* be1  = (const float*)d_in[7];
  const float* We2  = (const float*)d_in[8];
  const float* be2  = (const float*)d_in[9];
  float* out = (float*)d_out;

  const int* row = ei;
  const int* col = ei + NE;

  char* ws = (char*)d_ws;
  const size_t HB16 = (size_t)NN * 32 * 2;          // 6.4 MB
  __half*       h16a = (__half*)(ws);               // [0, 6.4)   (u aliases later)
  __half*       u    = (__half*)(ws);               // after h16a dead
  __half*       h16b = (__half*)(ws + HB16);        // [6.4, 12.8)
  unsigned int* keys = (unsigned int*)(ws + 2 * HB16);        // 10 MB
  float*        agg  = (float*)(ws + 2 * HB16 + 10000000);    // 12.8 MB
  __half*       v    = (__half*)(ws + 2 * HB16 + 22800000);   // 6.4 MB
  char*         tail = ws + 2 * HB16 + 29200000;
  int*          btot      = (int*)(tail);                     // NBUCK
  int*          bbase     = (int*)(tail + 6400);              // NBUCK+1
  int*          blockhist = (int*)(tail + 12800);             // NBLK_A*NBUCK (1.91MB)

  const int NB = (NN + 255) / 256;

  hipMemsetAsync(btot, 0, NBUCK * 4, stream);
  k_node_embed16<<<NB, 256, 0, stream>>>(nf, Win, bin, h16a);
  k_histA<<<NBLK_A, 512, 0, stream>>>(row, btot, blockhist);
  k_scanA<<<1, 1024, 0, stream>>>(btot, bbase);
  k_colscan<<<NBUCK, 512, 0, stream>>>(blockhist, bbase);
  k_partition<<<NBLK_A, 512, 0, stream>>>(row, col, blockhist, keys);

  k_bucket_agg<<<NBUCK, 256, 0, stream>>>(bbase, keys, h16a, agg);
  k_update<<<NB, 256, 0, stream>>>(h16a, agg, Wupd, bupd, h16b);

  k_bucket_agg<<<NBUCK, 256, 0, stream>>>(bbase, keys, h16b, agg);
  k_update2_uv<<<NB, 256, 0, stream>>>(h16b, agg, Wupd + 2048, bupd + 32,
                                       We1, be1, u, v);

  k_flux<<<(NE * 4 + 255) / 256, 256, 0, stream>>>(row, col, u, v, We2, be2, out);
}

// Round 8
// 258.388 us; speedup vs baseline: 4.2624x; 4.2624x over previous
//
#include <hip/hip_runtime.h>
#include <hip/hip_fp16.h>

#define NN 100000
#define NE 2500000
#define RANGE 256
#define NBUCK 391                       // ceil(NN/256)
#define CHUNK 8192
#define NBLK_A ((NE + CHUNK - 1) / CHUNK)   // 306
#define BCAP 8192                       // passB LDS stage cap (mean 6400, sd 80)

__device__ __forceinline__ float relu_(float x){ return fmaxf(x, 0.f); }

// h16[n,0:32] = relu(nf[n,0:2] @ W_in + b_in)  (fp16 master)
__global__ __launch_bounds__(256) void k_node_embed16(
    const float* __restrict__ nf, const float* __restrict__ Win,
    const float* __restrict__ bin, __half* __restrict__ h16)
{
  int n = blockIdx.x * 256 + threadIdx.x;
  if (n >= NN) return;
  float f0 = nf[2*n], f1 = nf[2*n+1];
  const float4* W0 = (const float4*)Win;
  const float4* W1 = (const float4*)(Win + 32);
  const float4* B  = (const float4*)bin;
  __half2* g2 = (__half2*)(h16 + (size_t)n * 32);
#pragma unroll
  for (int j = 0; j < 8; ++j) {
    float4 w0 = W0[j], w1 = W1[j], b = B[j], r;
    r.x = relu_(fmaf(f0, w0.x, fmaf(f1, w1.x, b.x)));
    r.y = relu_(fmaf(f0, w0.y, fmaf(f1, w1.y, b.y)));
    r.z = relu_(fmaf(f0, w0.z, fmaf(f1, w1.z, b.z)));
    r.w = relu_(fmaf(f0, w0.w, fmaf(f1, w1.w, b.w)));
    g2[2*j]   = __floats2half2_rn(r.x, r.y);
    g2[2*j+1] = __floats2half2_rn(r.z, r.w);
  }
}

// ---- CSR build: counting sort, per-block histograms persisted ----

__global__ __launch_bounds__(512) void k_histA(const int* __restrict__ row,
                                               int* __restrict__ btot,
                                               int* __restrict__ blockhist)
{
  __shared__ int hist[NBUCK];
  int t = threadIdx.x;
  for (int i = t; i < NBUCK; i += 512) hist[i] = 0;
  __syncthreads();
  int e0 = blockIdx.x * CHUNK + t;
#pragma unroll
  for (int k = 0; k < CHUNK / 512; ++k) {
    int e = e0 + k * 512;
    if (e < NE) atomicAdd(&hist[row[e] >> 8], 1);
  }
  __syncthreads();
  for (int i = t; i < NBUCK; i += 512) {
    int c = hist[i];
    blockhist[(size_t)i * NBLK_A + blockIdx.x] = c;
    if (c) atomicAdd(&btot[i], c);
  }
}

__global__ __launch_bounds__(512) void k_scanA(const int* __restrict__ btot,
                                               int* __restrict__ bbase)
{
  __shared__ int s[512];
  int t = threadIdx.x;
  int my = (t < NBUCK) ? btot[t] : 0;
  s[t] = my;
  __syncthreads();
  for (int off = 1; off < 512; off <<= 1) {
    int v = (t >= off) ? s[t - off] : 0;
    __syncthreads();
    s[t] += v;
    __syncthreads();
  }
  if (t < NBUCK) bbase[t] = s[t] - my;
  if (t == 0) bbase[NBUCK] = NE;
}

__global__ __launch_bounds__(512) void k_colscan(int* __restrict__ blockhist,
                                                 const int* __restrict__ bbase)
{
  __shared__ int s[512];
  int i = blockIdx.x, t = threadIdx.x;
  int* rowp = blockhist + (size_t)i * NBLK_A;
  int my = (t < NBLK_A) ? rowp[t] : 0;
  s[t] = my;
  __syncthreads();
  for (int off = 1; off < 512; off <<= 1) {
    int v = (t >= off) ? s[t - off] : 0;
    __syncthreads();
    s[t] += v;
    __syncthreads();
  }
  if (t < NBLK_A) rowp[t] = bbase[i] + s[t] - my;
}

__global__ __launch_bounds__(512) void k_partition(
    const int* __restrict__ row, const int* __restrict__ col,
    const int* __restrict__ blockhist, unsigned int* __restrict__ keys)
{
  __shared__ int cur[NBUCK];
  __shared__ int base[NBUCK];
  int t = threadIdx.x, b = blockIdx.x;
  for (int i = t; i < NBUCK; i += 512) {
    base[i] = blockhist[(size_t)i * NBLK_A + b];
    cur[i] = 0;
  }
  __syncthreads();
  int e0 = b * CHUNK + t;
#pragma unroll
  for (int k = 0; k < CHUNK / 512; ++k) {
    int e = e0 + k * 512;
    if (e < NE) {
      int r = row[e];
      int bi = r >> 8;
      int idx = atomicAdd(&cur[bi], 1);
      keys[base[bi] + idx] = ((unsigned)col[e] << 8) | (unsigned)(r & 255);
    }
  }
}

// per-bucket: single global key read (LDS-staged), histogram+scan -> rowptr, place ecol
__global__ __launch_bounds__(512) void k_passB(
    const int* __restrict__ bbase, const unsigned int* __restrict__ keys,
    int* __restrict__ ecol, int* __restrict__ rowptr)
{
  __shared__ unsigned keysl[BCAP];
  __shared__ int hist[RANGE];
  __shared__ int sc[RANGE];
  int t = threadIdx.x, b = blockIdx.x;
  int s0 = bbase[b], e0 = bbase[b + 1];
  int cnt = e0 - s0;
  if (t < RANGE) hist[t] = 0;
  __syncthreads();
  for (int i = t; i < cnt; i += 512) {
    unsigned k = keys[s0 + i];
    if (i < BCAP) keysl[i] = k;
    atomicAdd(&hist[k & 255u], 1);
  }
  __syncthreads();
  int my = (t < RANGE) ? hist[t] : 0;
  if (t < RANGE) sc[t] = my;
  __syncthreads();
  for (int off = 1; off < RANGE; off <<= 1) {
    int v = 0;
    if (t < RANGE && t >= off) v = sc[t - off];
    __syncthreads();
    if (t < RANGE) sc[t] += v;
    __syncthreads();
  }
  if (t < RANGE) {
    int ex = sc[t] - my;
    int n = b * RANGE + t;
    if (n <= NN) rowptr[n] = s0 + ex;
    hist[t] = ex;                 // placement cursor
  }
  __syncthreads();
  for (int i = t; i < cnt; i += 512) {
    unsigned key = (i < BCAP) ? keysl[i] : keys[s0 + i];
    int rl = (int)(key & 255u);
    int idx = atomicAdd(&hist[rl], 1);
    ecol[s0 + idx] = (int)(key >> 8);
  }
}

// ---- aggregation: agg16[n,:] = mean h16[ecol[i],:]  (4 lanes/node, 2-way unrolled) ----
__global__ __launch_bounds__(256) void k_aggregate(
    const int* __restrict__ rowptr, const int* __restrict__ ecol,
    const __half* __restrict__ h16, __half* __restrict__ agg16)
{
  int gid = blockIdx.x * 256 + threadIdx.x;
  int n = gid >> 2, q = gid & 3;
  if (n >= NN) return;
  int s = rowptr[n], e = rowptr[n + 1];
  const uint4* hv = (const uint4*)h16;
  float acc[8];
#pragma unroll
  for (int j = 0; j < 8; ++j) acc[j] = 0.f;
  int i = s;
  for (; i + 2 <= e; i += 2) {
    int c0 = ecol[i], c1 = ecol[i + 1];
    uint4 x0 = hv[c0 * 4 + q];
    uint4 x1 = hv[c1 * 4 + q];
    const __half2* p0 = (const __half2*)&x0;
    const __half2* p1 = (const __half2*)&x1;
#pragma unroll
    for (int k = 0; k < 4; ++k) {
      float2 f0 = __half22float2(p0[k]);
      float2 f1 = __half22float2(p1[k]);
      acc[2*k]   += f0.x + f1.x;
      acc[2*k+1] += f0.y + f1.y;
    }
  }
  if (i < e) {
    uint4 x = hv[ecol[i] * 4 + q];
    const __half2* hp = (const __half2*)&x;
#pragma unroll
    for (int k = 0; k < 4; ++k) {
      float2 f = __half22float2(hp[k]);
      acc[2*k] += f.x; acc[2*k+1] += f.y;
    }
  }
  float dinv = 1.0f / fmaxf((float)(e - s), 1.0f);
  uint4 pk;
  __half2* pp = (__half2*)&pk;
#pragma unroll
  for (int k = 0; k < 4; ++k)
    pp[k] = __floats2half2_rn(acc[2*k] * dinv, acc[2*k+1] * dinv);
  ((uint4*)agg16)[(size_t)n * 4 + q] = pk;
}

// layer-1 update: h16out = relu(concat(h16in, agg16) @ W + b)
__global__ __launch_bounds__(256) void k_update(
    const __half* __restrict__ h16in, const __half* __restrict__ agg16,
    const float* __restrict__ W, const float* __restrict__ b,
    __half* __restrict__ h16out)
{
  __shared__ float Ws[2048];
  __shared__ float bs[32];
  int t = threadIdx.x;
  for (int i = t; i < 2048; i += 256) Ws[i] = W[i];
  if (t < 32) bs[t] = b[t];
  __syncthreads();
  int n = blockIdx.x * 256 + t;
  if (n >= NN) return;

  float x[64];
  const uint4* hv = (const uint4*)(h16in + (size_t)n * 32);
  const uint4* av = (const uint4*)(agg16 + (size_t)n * 32);
#pragma unroll
  for (int j = 0; j < 4; ++j) {
    uint4 hx = hv[j], ax = av[j];
    const __half2* hp = (const __half2*)&hx;
    const __half2* ap = (const __half2*)&ax;
#pragma unroll
    for (int k = 0; k < 4; ++k) {
      float2 f = __half22float2(hp[k]);
      float2 g = __half22float2(ap[k]);
      x[j*8 + 2*k]      = f.x;
      x[j*8 + 2*k + 1]  = f.y;
      x[32 + j*8 + 2*k]     = g.x;
      x[32 + j*8 + 2*k + 1] = g.y;
    }
  }
  float acc[32];
#pragma unroll
  for (int j = 0; j < 32; ++j) acc[j] = bs[j];
#pragma unroll
  for (int k = 0; k < 64; ++k) {
    float xk = x[k];
    const float* wr = Ws + k * 32;
#pragma unroll
    for (int j = 0; j < 32; ++j) acc[j] = fmaf(xk, wr[j], acc[j]);
  }
  __half2* g2 = (__half2*)(h16out + (size_t)n * 32);
#pragma unroll
  for (int j = 0; j < 16; ++j)
    g2[j] = __floats2half2_rn(relu_(acc[2*j]), relu_(acc[2*j+1]));
}

// layer-2 update fused with edge projection: u = h2@We1[0:32]+be1, v = h2@We1[32:64]
__global__ __launch_bounds__(256) void k_update2_uv(
    const __half* __restrict__ h16in, const __half* __restrict__ agg16,
    const float* __restrict__ W, const float* __restrict__ b,
    const float* __restrict__ We1, const float* __restrict__ be1,
    __half* __restrict__ u, __half* __restrict__ v)
{
  __shared__ float Ws[2048];
  __shared__ float Es[2048];
  __shared__ float bs[32];
  __shared__ float bes[32];
  int t = threadIdx.x;
  for (int i = t; i < 2048; i += 256) { Ws[i] = W[i]; Es[i] = We1[i]; }
  if (t < 32) { bs[t] = b[t]; bes[t] = be1[t]; }
  __syncthreads();
  int n = blockIdx.x * 256 + t;
  if (n >= NN) return;

  float x[64];
  const uint4* hv = (const uint4*)(h16in + (size_t)n * 32);
  const uint4* av = (const uint4*)(agg16 + (size_t)n * 32);
#pragma unroll
  for (int j = 0; j < 4; ++j) {
    uint4 hx = hv[j], ax = av[j];
    const __half2* hp = (const __half2*)&hx;
    const __half2* ap = (const __half2*)&ax;
#pragma unroll
    for (int k = 0; k < 4; ++k) {
      float2 f = __half22float2(hp[k]);
      float2 g = __half22float2(ap[k]);
      x[j*8 + 2*k]      = f.x;
      x[j*8 + 2*k + 1]  = f.y;
      x[32 + j*8 + 2*k]     = g.x;
      x[32 + j*8 + 2*k + 1] = g.y;
    }
  }
  float h2[32];
#pragma unroll
  for (int j = 0; j < 32; ++j) h2[j] = bs[j];
#pragma unroll
  for (int k = 0; k < 64; ++k) {
    float xk = x[k];
    const float* wr = Ws + k * 32;
#pragma unroll
    for (int j = 0; j < 32; ++j) h2[j] = fmaf(xk, wr[j], h2[j]);
  }
#pragma unroll
  for (int j = 0; j < 32; ++j) h2[j] = relu_(h2[j]);

  float au[32], av2[32];
#pragma unroll
  for (int j = 0; j < 32; ++j) { au[j] = bes[j]; av2[j] = 0.f; }
#pragma unroll
  for (int k = 0; k < 32; ++k) {
    float hk = h2[k];
    const float* wu = Es + k * 32;
    const float* wv = Es + (32 + k) * 32;
#pragma unroll
    for (int j = 0; j < 32; ++j) {
      au[j] = fmaf(hk, wu[j], au[j]);
      av2[j] = fmaf(hk, wv[j], av2[j]);
    }
  }
  __half2* u2 = (__half2*)(u + (size_t)n * 32);
  __half2* v2 = (__half2*)(v + (size_t)n * 32);
#pragma unroll
  for (int j = 0; j < 16; ++j) {
    u2[j] = __floats2half2_rn(au[2*j], au[2*j+1]);
    v2[j] = __floats2half2_rn(av2[2*j], av2[2*j+1]);
  }
}

// flux[e] = relu(u[row]+v[col]).We2 + be2   (4 lanes/edge, uint4 fp16 loads)
__global__ __launch_bounds__(256) void k_flux(
    const int* __restrict__ row, const int* __restrict__ col,
    const __half* __restrict__ u, const __half* __restrict__ v,
    const float* __restrict__ We2, const float* __restrict__ be2,
    float* __restrict__ out)
{
  int gid = blockIdx.x * 256 + threadIdx.x;
  int e = gid >> 2, q = gid & 3;
  if (e >= NE) return;
  int r = row[e], c = col[e];
  uint4 ua = ((const uint4*)u)[r * 4 + q];   // 8 halfs
  uint4 vb = ((const uint4*)v)[c * 4 + q];
  const __half2* ah = (const __half2*)&ua;
  const __half2* bh = (const __half2*)&vb;
  const float4* w4 = (const float4*)(We2 + q * 8);
  float4 w0 = w4[0], w1 = w4[1];
  float p = 0.f;
  {
    float2 a = __half22float2(ah[0]), b = __half22float2(bh[0]);
    p += relu_(a.x + b.x) * w0.x + relu_(a.y + b.y) * w0.y;
    a = __half22float2(ah[1]); b = __half22float2(bh[1]);
    p += relu_(a.x + b.x) * w0.z + relu_(a.y + b.y) * w0.w;
    a = __half22float2(ah[2]); b = __half22float2(bh[2]);
    p += relu_(a.x + b.x) * w1.x + relu_(a.y + b.y) * w1.y;
    a = __half22float2(ah[3]); b = __half22float2(bh[3]);
    p += relu_(a.x + b.x) * w1.z + relu_(a.y + b.y) * w1.w;
  }
  p += __shfl_xor(p, 1, 4);
  p += __shfl_xor(p, 2, 4);
  if (q == 0) out[e] = p + be2[0];
}

extern "C" void kernel_launch(void* const* d_in, const int* in_sizes, int n_in,
                              void* d_out, int out_size, void* d_ws, size_t ws_size,
                              hipStream_t stream) {
  const float* nf   = (const float*)d_in[0];
  const int*   ei   = (const int*)d_in[1];
  const float* Win  = (const float*)d_in[2];
  const float* bin  = (const float*)d_in[3];
  const float* Wupd = (const float*)d_in[4];
  const float* bupd = (const float*)d_in[5];
  const float* We1  = (const float*)d_in[6];
  const float* be1  = (const float*)d_in[7];
  const float* We2  = (const float*)d_in[8];
  const float* be2  = (const float*)d_in[9];
  float* out = (float*)d_out;

  const int* row = ei;
  const int* col = ei + NE;

  char* ws = (char*)d_ws;
  const size_t HB16 = (size_t)NN * 32 * 2;            // 6.4 MB
  __half*       h16a  = (__half*)(ws);                // [0, 6.4)
  __half*       u     = (__half*)(ws);                // aliases h16a (dead after update1)
  __half*       h16b  = (__half*)(ws + HB16);         // [6.4, 12.8)
  unsigned int* keys  = (unsigned int*)(ws + 2 * HB16);           // 10 MB
  int*          ecol  = (int*)(ws + 2 * HB16 + 10000000);         // 10 MB
  __half*       agg16 = (__half*)(ws + 2 * HB16 + 20000000);      // 6.4 MB
  __half*       v     = (__half*)(ws + 2 * HB16 + 20000000 + HB16); // 6.4 MB
  char*         tail  = ws + 2 * HB16 + 20000000 + 2 * HB16;
  int*          rowptr    = (int*)(tail);                          // NN+1
  int*          btot      = (int*)(tail + 400512);
  int*          bbase     = (int*)(tail + 402560);
  int*          blockhist = (int*)(tail + 404608);                 // NBUCK*NBLK_A

  const int NB = (NN + 255) / 256;

  hipMemsetAsync(btot, 0, NBUCK * 4, stream);
  k_node_embed16<<<NB, 256, 0, stream>>>(nf, Win, bin, h16a);
  k_histA<<<NBLK_A, 512, 0, stream>>>(row, btot, blockhist);
  k_scanA<<<1, 512, 0, stream>>>(btot, bbase);
  k_colscan<<<NBUCK, 512, 0, stream>>>(blockhist, bbase);
  k_partition<<<NBLK_A, 512, 0, stream>>>(row, col, blockhist, keys);
  k_passB<<<NBUCK, 512, 0, stream>>>(bbase, keys, ecol, rowptr);

  k_aggregate<<<(NN * 4 + 255) / 256, 256, 0, stream>>>(rowptr, ecol, h16a, agg16);
  k_update<<<NB, 256, 0, stream>>>(h16a, agg16, Wupd, bupd, h16b);

  k_aggregate<<<(NN * 4 + 255) / 256, 256, 0, stream>>>(rowptr, ecol, h16b, agg16);
  k_update2_uv<<<NB, 256, 0, stream>>>(h16b, agg16, Wupd + 2048, bupd + 32,
                                       We1, be1, u, v);

  k_flux<<<(NE * 4 + 255) / 256, 256, 0, stream>>>(row, col, u, v, We2, be2, out);
}

// Round 9
// 245.069 us; speedup vs baseline: 4.4941x; 1.0543x over previous
//
#include <hip/hip_runtime.h>
#include <hip/hip_fp16.h>

#define NN 100000
#define NE 2500000
#define RANGE 256
#define NBUCK 391                       // ceil(NN/256)
#define CHUNK 8192
#define NBLK_A ((NE + CHUNK - 1) / CHUNK)   // 306
#define BCAP 8192                       // passB LDS stage cap (mean 6400, sd 80)

__device__ __forceinline__ float relu_(float x){ return fmaxf(x, 0.f); }

// h16[n,0:32] = relu(nf[n,0:2] @ W_in + b_in)  (fp16 master)
__global__ __launch_bounds__(256) void k_node_embed16(
    const float* __restrict__ nf, const float* __restrict__ Win,
    const float* __restrict__ bin, __half* __restrict__ h16)
{
  int n = blockIdx.x * 256 + threadIdx.x;
  if (n >= NN) return;
  float f0 = nf[2*n], f1 = nf[2*n+1];
  const float4* W0 = (const float4*)Win;
  const float4* W1 = (const float4*)(Win + 32);
  const float4* B  = (const float4*)bin;
  __half2* g2 = (__half2*)(h16 + (size_t)n * 32);
#pragma unroll
  for (int j = 0; j < 8; ++j) {
    float4 w0 = W0[j], w1 = W1[j], b = B[j], r;
    r.x = relu_(fmaf(f0, w0.x, fmaf(f1, w1.x, b.x)));
    r.y = relu_(fmaf(f0, w0.y, fmaf(f1, w1.y, b.y)));
    r.z = relu_(fmaf(f0, w0.z, fmaf(f1, w1.z, b.z)));
    r.w = relu_(fmaf(f0, w0.w, fmaf(f1, w1.w, b.w)));
    g2[2*j]   = __floats2half2_rn(r.x, r.y);
    g2[2*j+1] = __floats2half2_rn(r.z, r.w);
  }
}

// ---- CSR build: counting sort, per-block histograms persisted ----

__global__ __launch_bounds__(512) void k_histA(const int* __restrict__ row,
                                               int* __restrict__ btot,
                                               int* __restrict__ blockhist)
{
  __shared__ int hist[NBUCK];
  int t = threadIdx.x;
  for (int i = t; i < NBUCK; i += 512) hist[i] = 0;
  __syncthreads();
  int e0 = blockIdx.x * CHUNK + t;
#pragma unroll
  for (int k = 0; k < CHUNK / 512; ++k) {
    int e = e0 + k * 512;
    if (e < NE) atomicAdd(&hist[row[e] >> 8], 1);
  }
  __syncthreads();
  for (int i = t; i < NBUCK; i += 512) {
    int c = hist[i];
    blockhist[(size_t)i * NBLK_A + blockIdx.x] = c;
    if (c) atomicAdd(&btot[i], c);
  }
}

__global__ __launch_bounds__(512) void k_scanA(const int* __restrict__ btot,
                                               int* __restrict__ bbase)
{
  __shared__ int s[512];
  int t = threadIdx.x;
  int my = (t < NBUCK) ? btot[t] : 0;
  s[t] = my;
  __syncthreads();
  for (int off = 1; off < 512; off <<= 1) {
    int v = (t >= off) ? s[t - off] : 0;
    __syncthreads();
    s[t] += v;
    __syncthreads();
  }
  if (t < NBUCK) bbase[t] = s[t] - my;
  if (t == 0) bbase[NBUCK] = NE;
}

__global__ __launch_bounds__(512) void k_colscan(int* __restrict__ blockhist,
                                                 const int* __restrict__ bbase)
{
  __shared__ int s[512];
  int i = blockIdx.x, t = threadIdx.x;
  int* rowp = blockhist + (size_t)i * NBLK_A;
  int my = (t < NBLK_A) ? rowp[t] : 0;
  s[t] = my;
  __syncthreads();
  for (int off = 1; off < 512; off <<= 1) {
    int v = (t >= off) ? s[t - off] : 0;
    __syncthreads();
    s[t] += v;
    __syncthreads();
  }
  if (t < NBLK_A) rowp[t] = bbase[i] + s[t] - my;
}

__global__ __launch_bounds__(512) void k_partition(
    const int* __restrict__ row, const int* __restrict__ col,
    const int* __restrict__ blockhist, unsigned int* __restrict__ keys)
{
  __shared__ int cur[NBUCK];
  __shared__ int base[NBUCK];
  int t = threadIdx.x, b = blockIdx.x;
  for (int i = t; i < NBUCK; i += 512) {
    base[i] = blockhist[(size_t)i * NBLK_A + b];
    cur[i] = 0;
  }
  __syncthreads();
  int e0 = b * CHUNK + t;
#pragma unroll
  for (int k = 0; k < CHUNK / 512; ++k) {
    int e = e0 + k * 512;
    if (e < NE) {
      int r = row[e];
      int bi = r >> 8;
      int idx = atomicAdd(&cur[bi], 1);
      keys[base[bi] + idx] = ((unsigned)col[e] << 8) | (unsigned)(r & 255);
    }
  }
}

// per-bucket: single global key read (LDS-staged), histogram+scan -> rowptr, place ecol
__global__ __launch_bounds__(512) void k_passB(
    const int* __restrict__ bbase, const unsigned int* __restrict__ keys,
    int* __restrict__ ecol, int* __restrict__ rowptr)
{
  __shared__ unsigned keysl[BCAP];
  __shared__ int hist[RANGE];
  __shared__ int sc[RANGE];
  int t = threadIdx.x, b = blockIdx.x;
  int s0 = bbase[b], e0 = bbase[b + 1];
  int cnt = e0 - s0;
  if (t < RANGE) hist[t] = 0;
  __syncthreads();
  for (int i = t; i < cnt; i += 512) {
    unsigned k = keys[s0 + i];
    if (i < BCAP) keysl[i] = k;
    atomicAdd(&hist[k & 255u], 1);
  }
  __syncthreads();
  int my = (t < RANGE) ? hist[t] : 0;
  if (t < RANGE) sc[t] = my;
  __syncthreads();
  for (int off = 1; off < RANGE; off <<= 1) {
    int v = 0;
    if (t < RANGE && t >= off) v = sc[t - off];
    __syncthreads();
    if (t < RANGE) sc[t] += v;
    __syncthreads();
  }
  if (t < RANGE) {
    int ex = sc[t] - my;
    int n = b * RANGE + t;
    if (n <= NN) rowptr[n] = s0 + ex;
    hist[t] = ex;                 // placement cursor
  }
  __syncthreads();
  for (int i = t; i < cnt; i += 512) {
    unsigned key = (i < BCAP) ? keysl[i] : keys[s0 + i];
    int rl = (int)(key & 255u);
    int idx = atomicAdd(&hist[rl], 1);
    ecol[s0 + idx] = (int)(key >> 8);
  }
}

// ---- layer-1 aggregation by RECOMPUTE: agg16[n,:] = mean_c relu(nf[c]@Win+bin)
//      nf is 800KB (L2-resident) -> 8B gathers instead of 64B h-vector gathers
__global__ __launch_bounds__(256) void k_agg1_recompute(
    const int* __restrict__ rowptr, const int* __restrict__ ecol,
    const float* __restrict__ nf, const float* __restrict__ Win,
    const float* __restrict__ bin, __half* __restrict__ agg16)
{
  int gid = blockIdx.x * 256 + threadIdx.x;
  int n = gid >> 2, q = gid & 3;
  if (n >= NN) return;
  float w0[8], w1[8], bb[8];
#pragma unroll
  for (int j = 0; j < 8; ++j) {
    w0[j] = Win[q * 8 + j];
    w1[j] = Win[32 + q * 8 + j];
    bb[j] = bin[q * 8 + j];
  }
  int s = rowptr[n], e = rowptr[n + 1];
  const float2* nf2 = (const float2*)nf;
  float acc[8];
#pragma unroll
  for (int j = 0; j < 8; ++j) acc[j] = 0.f;
  int i = s;
  for (; i + 2 <= e; i += 2) {
    int c0 = ecol[i], c1 = ecol[i + 1];
    float2 f0 = nf2[c0];
    float2 f1 = nf2[c1];
#pragma unroll
    for (int j = 0; j < 8; ++j) {
      acc[j] += relu_(fmaf(f0.x, w0[j], fmaf(f0.y, w1[j], bb[j])));
      acc[j] += relu_(fmaf(f1.x, w0[j], fmaf(f1.y, w1[j], bb[j])));
    }
  }
  if (i < e) {
    float2 f = nf2[ecol[i]];
#pragma unroll
    for (int j = 0; j < 8; ++j)
      acc[j] += relu_(fmaf(f.x, w0[j], fmaf(f.y, w1[j], bb[j])));
  }
  float dinv = 1.0f / fmaxf((float)(e - s), 1.0f);
  uint4 pk;
  __half2* pp = (__half2*)&pk;
#pragma unroll
  for (int k = 0; k < 4; ++k)
    pp[k] = __floats2half2_rn(acc[2*k] * dinv, acc[2*k+1] * dinv);
  ((uint4*)agg16)[(size_t)n * 4 + q] = pk;
}

// ---- layer-2 aggregation: agg16[n,:] = mean h16[ecol[i],:] (4 lanes/node, 2-way) ----
__global__ __launch_bounds__(256) void k_aggregate(
    const int* __restrict__ rowptr, const int* __restrict__ ecol,
    const __half* __restrict__ h16, __half* __restrict__ agg16)
{
  int gid = blockIdx.x * 256 + threadIdx.x;
  int n = gid >> 2, q = gid & 3;
  if (n >= NN) return;
  int s = rowptr[n], e = rowptr[n + 1];
  const uint4* hv = (const uint4*)h16;
  float acc[8];
#pragma unroll
  for (int j = 0; j < 8; ++j) acc[j] = 0.f;
  int i = s;
  for (; i + 2 <= e; i += 2) {
    int c0 = ecol[i], c1 = ecol[i + 1];
    uint4 x0 = hv[c0 * 4 + q];
    uint4 x1 = hv[c1 * 4 + q];
    const __half2* p0 = (const __half2*)&x0;
    const __half2* p1 = (const __half2*)&x1;
#pragma unroll
    for (int k = 0; k < 4; ++k) {
      float2 f0 = __half22float2(p0[k]);
      float2 f1 = __half22float2(p1[k]);
      acc[2*k]   += f0.x + f1.x;
      acc[2*k+1] += f0.y + f1.y;
    }
  }
  if (i < e) {
    uint4 x = hv[ecol[i] * 4 + q];
    const __half2* hp = (const __half2*)&x;
#pragma unroll
    for (int k = 0; k < 4; ++k) {
      float2 f = __half22float2(hp[k]);
      acc[2*k] += f.x; acc[2*k+1] += f.y;
    }
  }
  float dinv = 1.0f / fmaxf((float)(e - s), 1.0f);
  uint4 pk;
  __half2* pp = (__half2*)&pk;
#pragma unroll
  for (int k = 0; k < 4; ++k)
    pp[k] = __floats2half2_rn(acc[2*k] * dinv, acc[2*k+1] * dinv);
  ((uint4*)agg16)[(size_t)n * 4 + q] = pk;
}

// layer-1 update: h16out = relu(concat(h16in, agg16) @ W + b)
__global__ __launch_bounds__(256) void k_update(
    const __half* __restrict__ h16in, const __half* __restrict__ agg16,
    const float* __restrict__ W, const float* __restrict__ b,
    __half* __restrict__ h16out)
{
  __shared__ float Ws[2048];
  __shared__ float bs[32];
  int t = threadIdx.x;
  for (int i = t; i < 2048; i += 256) Ws[i] = W[i];
  if (t < 32) bs[t] = b[t];
  __syncthreads();
  int n = blockIdx.x * 256 + t;
  if (n >= NN) return;

  float x[64];
  const uint4* hv = (const uint4*)(h16in + (size_t)n * 32);
  const uint4* av = (const uint4*)(agg16 + (size_t)n * 32);
#pragma unroll
  for (int j = 0; j < 4; ++j) {
    uint4 hx = hv[j], ax = av[j];
    const __half2* hp = (const __half2*)&hx;
    const __half2* ap = (const __half2*)&ax;
#pragma unroll
    for (int k = 0; k < 4; ++k) {
      float2 f = __half22float2(hp[k]);
      float2 g = __half22float2(ap[k]);
      x[j*8 + 2*k]      = f.x;
      x[j*8 + 2*k + 1]  = f.y;
      x[32 + j*8 + 2*k]     = g.x;
      x[32 + j*8 + 2*k + 1] = g.y;
    }
  }
  float acc[32];
#pragma unroll
  for (int j = 0; j < 32; ++j) acc[j] = bs[j];
#pragma unroll
  for (int k = 0; k < 64; ++k) {
    float xk = x[k];
    const float* wr = Ws + k * 32;
#pragma unroll
    for (int j = 0; j < 32; ++j) acc[j] = fmaf(xk, wr[j], acc[j]);
  }
  __half2* g2 = (__half2*)(h16out + (size_t)n * 32);
#pragma unroll
  for (int j = 0; j < 16; ++j)
    g2[j] = __floats2half2_rn(relu_(acc[2*j]), relu_(acc[2*j+1]));
}

// layer-2 update fused with edge projection: u = h2@We1[0:32]+be1, v = h2@We1[32:64]
__global__ __launch_bounds__(256) void k_update2_uv(
    const __half* __restrict__ h16in, const __half* __restrict__ agg16,
    const float* __restrict__ W, const float* __restrict__ b,
    const float* __restrict__ We1, const float* __restrict__ be1,
    __half* __restrict__ u, __half* __restrict__ v)
{
  __shared__ float Ws[2048];
  __shared__ float Es[2048];
  __shared__ float bs[32];
  __shared__ float bes[32];
  int t = threadIdx.x;
  for (int i = t; i < 2048; i += 256) { Ws[i] = W[i]; Es[i] = We1[i]; }
  if (t < 32) { bs[t] = b[t]; bes[t] = be1[t]; }
  __syncthreads();
  int n = blockIdx.x * 256 + t;
  if (n >= NN) return;

  float x[64];
  const uint4* hv = (const uint4*)(h16in + (size_t)n * 32);
  const uint4* av = (const uint4*)(agg16 + (size_t)n * 32);
#pragma unroll
  for (int j = 0; j < 4; ++j) {
    uint4 hx = hv[j], ax = av[j];
    const __half2* hp = (const __half2*)&hx;
    const __half2* ap = (const __half2*)&ax;
#pragma unroll
    for (int k = 0; k < 4; ++k) {
      float2 f = __half22float2(hp[k]);
      float2 g = __half22float2(ap[k]);
      x[j*8 + 2*k]      = f.x;
      x[j*8 + 2*k + 1]  = f.y;
      x[32 + j*8 + 2*k]     = g.x;
      x[32 + j*8 + 2*k + 1] = g.y;
    }
  }
  float h2[32];
#pragma unroll
  for (int j = 0; j < 32; ++j) h2[j] = bs[j];
#pragma unroll
  for (int k = 0; k < 64; ++k) {
    float xk = x[k];
    const float* wr = Ws + k * 32;
#pragma unroll
    for (int j = 0; j < 32; ++j) h2[j] = fmaf(xk, wr[j], h2[j]);
  }
#pragma unroll
  for (int j = 0; j < 32; ++j) h2[j] = relu_(h2[j]);

  float au[32], av2[32];
#pragma unroll
  for (int j = 0; j < 32; ++j) { au[j] = bes[j]; av2[j] = 0.f; }
#pragma unroll
  for (int k = 0; k < 32; ++k) {
    float hk = h2[k];
    const float* wu = Es + k * 32;
    const float* wv = Es + (32 + k) * 32;
#pragma unroll
    for (int j = 0; j < 32; ++j) {
      au[j] = fmaf(hk, wu[j], au[j]);
      av2[j] = fmaf(hk, wv[j], av2[j]);
    }
  }
  __half2* u2 = (__half2*)(u + (size_t)n * 32);
  __half2* v2 = (__half2*)(v + (size_t)n * 32);
#pragma unroll
  for (int j = 0; j < 16; ++j) {
    u2[j] = __floats2half2_rn(au[2*j], au[2*j+1]);
    v2[j] = __floats2half2_rn(av2[2*j], av2[2*j+1]);
  }
}

// flux: 2 edges per 4-lane group, all 4 gathers issued before use (MLP)
__global__ __launch_bounds__(256) void k_flux(
    const int* __restrict__ row, const int* __restrict__ col,
    const __half* __restrict__ u, const __half* __restrict__ v,
    const float* __restrict__ We2, const float* __restrict__ be2,
    float* __restrict__ out)
{
  int gid = blockIdx.x * 256 + threadIdx.x;
  int pr = gid >> 2, q = gid & 3;
  int e0 = pr * 2, e1 = pr * 2 + 1;
  if (e0 >= NE) return;
  bool has1 = (e1 < NE);
  int r0 = row[e0], c0 = col[e0];
  int r1 = has1 ? row[e1] : r0;
  int c1 = has1 ? col[e1] : c0;
  const uint4* U = (const uint4*)u;
  const uint4* V = (const uint4*)v;
  uint4 ua0 = U[r0 * 4 + q];
  uint4 vb0 = V[c0 * 4 + q];
  uint4 ua1 = U[r1 * 4 + q];
  uint4 vb1 = V[c1 * 4 + q];
  const float4* w4 = (const float4*)(We2 + q * 8);
  float4 w0 = w4[0], w1 = w4[1];
  float bias = be2[0];

  const __half2* ah = (const __half2*)&ua0;
  const __half2* bh = (const __half2*)&vb0;
  float p0 = 0.f;
  {
    float2 a = __half22float2(ah[0]), b = __half22float2(bh[0]);
    p0 += relu_(a.x + b.x) * w0.x + relu_(a.y + b.y) * w0.y;
    a = __half22float2(ah[1]); b = __half22float2(bh[1]);
    p0 += relu_(a.x + b.x) * w0.z + relu_(a.y + b.y) * w0.w;
    a = __half22float2(ah[2]); b = __half22float2(bh[2]);
    p0 += relu_(a.x + b.x) * w1.x + relu_(a.y + b.y) * w1.y;
    a = __half22float2(ah[3]); b = __half22float2(bh[3]);
    p0 += relu_(a.x + b.x) * w1.z + relu_(a.y + b.y) * w1.w;
  }
  const __half2* ah1 = (const __half2*)&ua1;
  const __half2* bh1 = (const __half2*)&vb1;
  float p1 = 0.f;
  {
    float2 a = __half22float2(ah1[0]), b = __half22float2(bh1[0]);
    p1 += relu_(a.x + b.x) * w0.x + relu_(a.y + b.y) * w0.y;
    a = __half22float2(ah1[1]); b = __half22float2(bh1[1]);
    p1 += relu_(a.x + b.x) * w0.z + relu_(a.y + b.y) * w0.w;
    a = __half22float2(ah1[2]); b = __half22float2(bh1[2]);
    p1 += relu_(a.x + b.x) * w1.x + relu_(a.y + b.y) * w1.y;
    a = __half22float2(ah1[3]); b = __half22float2(bh1[3]);
    p1 += relu_(a.x + b.x) * w1.z + relu_(a.y + b.y) * w1.w;
  }
  p0 += __shfl_xor(p0, 1, 4);
  p0 += __shfl_xor(p0, 2, 4);
  p1 += __shfl_xor(p1, 1, 4);
  p1 += __shfl_xor(p1, 2, 4);
  if (q == 0) {
    out[e0] = p0 + bias;
    if (has1) out[e1] = p1 + bias;
  }
}

extern "C" void kernel_launch(void* const* d_in, const int* in_sizes, int n_in,
                              void* d_out, int out_size, void* d_ws, size_t ws_size,
                              hipStream_t stream) {
  const float* nf   = (const float*)d_in[0];
  const int*   ei   = (const int*)d_in[1];
  const float* Win  = (const float*)d_in[2];
  const float* bin  = (const float*)d_in[3];
  const float* Wupd = (const float*)d_in[4];
  const float* bupd = (const float*)d_in[5];
  const float* We1  = (const float*)d_in[6];
  const float* be1  = (const float*)d_in[7];
  const float* We2  = (const float*)d_in[8];
  const float* be2  = (const float*)d_in[9];
  float* out = (float*)d_out;

  const int* row = ei;
  const int* col = ei + NE;

  char* ws = (char*)d_ws;
  const size_t HB16 = (size_t)NN * 32 * 2;            // 6.4 MB
  __half*       h16a  = (__half*)(ws);                // [0, 6.4)
  __half*       u     = (__half*)(ws);                // aliases h16a (dead after update1)
  __half*       h16b  = (__half*)(ws + HB16);         // [6.4, 12.8)
  unsigned int* keys  = (unsigned int*)(ws + 2 * HB16);           // 10 MB
  int*          ecol  = (int*)(ws + 2 * HB16 + 10000000);         // 10 MB
  __half*       agg16 = (__half*)(ws + 2 * HB16 + 20000000);      // 6.4 MB
  __half*       v     = (__half*)(ws + 2 * HB16 + 20000000 + HB16); // 6.4 MB
  char*         tail  = ws + 2 * HB16 + 20000000 + 2 * HB16;
  int*          rowptr    = (int*)(tail);                          // NN+1
  int*          btot      = (int*)(tail + 400512);
  int*          bbase     = (int*)(tail + 402560);
  int*          blockhist = (int*)(tail + 404608);                 // NBUCK*NBLK_A

  const int NB = (NN + 255) / 256;

  hipMemsetAsync(btot, 0, NBUCK * 4, stream);
  k_node_embed16<<<NB, 256, 0, stream>>>(nf, Win, bin, h16a);
  k_histA<<<NBLK_A, 512, 0, stream>>>(row, btot, blockhist);
  k_scanA<<<1, 512, 0, stream>>>(btot, bbase);
  k_colscan<<<NBUCK, 512, 0, stream>>>(blockhist, bbase);
  k_partition<<<NBLK_A, 512, 0, stream>>>(row, col, blockhist, keys);
  k_passB<<<NBUCK, 512, 0, stream>>>(bbase, keys, ecol, rowptr);

  k_agg1_recompute<<<(NN * 4 + 255) / 256, 256, 0, stream>>>(rowptr, ecol, nf,
                                                             Win, bin, agg16);
  k_update<<<NB, 256, 0, stream>>>(h16a, agg16, Wupd, bupd, h16b);

  k_aggregate<<<(NN * 4 + 255) / 256, 256, 0, stream>>>(rowptr, ecol, h16b, agg16);
  k_update2_uv<<<NB, 256, 0, stream>>>(h16b, agg16, Wupd + 2048, bupd + 32,
                                       We1, be1, u, v);

  k_flux<<<(NE * 2 + 255) / 256, 256, 0, stream>>>(row, col, u, v, We2, be2, out);
}

// Round 10
// 236.861 us; speedup vs baseline: 4.6498x; 1.0347x over previous
//
#include <hip/hip_runtime.h>
#include <hip/hip_fp16.h>

#define NN 100000
#define NE 2500000
#define RANGE 256
#define NBUCK 391                       // ceil(NN/256)
#define CHUNK 16384
#define NBLK_A ((NE + CHUNK - 1) / CHUNK)   // 153
#define BCAP 8192                       // passB LDS stage cap (mean 6400, sd ~80)

__device__ __forceinline__ float relu_(float x){ return fmaxf(x, 0.f); }

// h16[n,0:32] = relu(nf[n,0:2] @ W_in + b_in)  (fp16 master)
__global__ __launch_bounds__(256) void k_node_embed16(
    const float* __restrict__ nf, const float* __restrict__ Win,
    const float* __restrict__ bin, __half* __restrict__ h16)
{
  int n = blockIdx.x * 256 + threadIdx.x;
  if (n >= NN) return;
  float f0 = nf[2*n], f1 = nf[2*n+1];
  const float4* W0 = (const float4*)Win;
  const float4* W1 = (const float4*)(Win + 32);
  const float4* B  = (const float4*)bin;
  __half2* g2 = (__half2*)(h16 + (size_t)n * 32);
#pragma unroll
  for (int j = 0; j < 8; ++j) {
    float4 w0 = W0[j], w1 = W1[j], b = B[j], r;
    r.x = relu_(fmaf(f0, w0.x, fmaf(f1, w1.x, b.x)));
    r.y = relu_(fmaf(f0, w0.y, fmaf(f1, w1.y, b.y)));
    r.z = relu_(fmaf(f0, w0.z, fmaf(f1, w1.z, b.z)));
    r.w = relu_(fmaf(f0, w0.w, fmaf(f1, w1.w, b.w)));
    g2[2*j]   = __floats2half2_rn(r.x, r.y);
    g2[2*j+1] = __floats2half2_rn(r.z, r.w);
  }
}

// ---- CSR build: counting sort, per-block histograms persisted ----

__global__ __launch_bounds__(512) void k_histA(const int* __restrict__ row,
                                               int* __restrict__ btot,
                                               int* __restrict__ blockhist)
{
  __shared__ int hist[NBUCK];
  int t = threadIdx.x;
  for (int i = t; i < NBUCK; i += 512) hist[i] = 0;
  __syncthreads();
  int e0 = blockIdx.x * CHUNK + t;
#pragma unroll
  for (int k = 0; k < CHUNK / 512; ++k) {
    int e = e0 + k * 512;
    if (e < NE) atomicAdd(&hist[row[e] >> 8], 1);
  }
  __syncthreads();
  for (int i = t; i < NBUCK; i += 512) {
    int c = hist[i];
    blockhist[(size_t)i * NBLK_A + blockIdx.x] = c;
    if (c) atomicAdd(&btot[i], c);
  }
}

__global__ __launch_bounds__(512) void k_scanA(const int* __restrict__ btot,
                                               int* __restrict__ bbase)
{
  __shared__ int s[512];
  int t = threadIdx.x;
  int my = (t < NBUCK) ? btot[t] : 0;
  s[t] = my;
  __syncthreads();
  for (int off = 1; off < 512; off <<= 1) {
    int v = (t >= off) ? s[t - off] : 0;
    __syncthreads();
    s[t] += v;
    __syncthreads();
  }
  if (t < NBUCK) bbase[t] = s[t] - my;
  if (t == 0) bbase[NBUCK] = NE;
}

__global__ __launch_bounds__(512) void k_colscan(int* __restrict__ blockhist,
                                                 const int* __restrict__ bbase)
{
  __shared__ int s[512];
  int i = blockIdx.x, t = threadIdx.x;
  int* rowp = blockhist + (size_t)i * NBLK_A;
  int my = (t < NBLK_A) ? rowp[t] : 0;
  s[t] = my;
  __syncthreads();
  for (int off = 1; off < 512; off <<= 1) {
    int v = (t >= off) ? s[t - off] : 0;
    __syncthreads();
    s[t] += v;
    __syncthreads();
  }
  if (t < NBLK_A) rowp[t] = bbase[i] + s[t] - my;
}

__global__ __launch_bounds__(512) void k_partition(
    const int* __restrict__ row, const int* __restrict__ col,
    const int* __restrict__ blockhist, unsigned int* __restrict__ keys)
{
  __shared__ int cur[NBUCK];
  __shared__ int base[NBUCK];
  int t = threadIdx.x, b = blockIdx.x;
  for (int i = t; i < NBUCK; i += 512) {
    base[i] = blockhist[(size_t)i * NBLK_A + b];
    cur[i] = 0;
  }
  __syncthreads();
  int e0 = b * CHUNK + t;
#pragma unroll
  for (int k = 0; k < CHUNK / 512; ++k) {
    int e = e0 + k * 512;
    if (e < NE) {
      int r = row[e];
      int bi = r >> 8;
      int idx = atomicAdd(&cur[bi], 1);
      keys[base[bi] + idx] = ((unsigned)col[e] << 8) | (unsigned)(r & 255);
    }
  }
}

// per-bucket: LDS-staged keys -> hist -> scan -> rowptr + ecol placement,
// then FUSED layer-1 aggregation by recompute:
// agg16[n,:] = mean_c relu(nf[c] @ Win + bin)   (nf 800KB, L2-resident)
__global__ __launch_bounds__(512) void k_passB_agg1(
    const int* __restrict__ bbase, const unsigned int* __restrict__ keys,
    const float* __restrict__ nf, const float* __restrict__ Win,
    const float* __restrict__ bin,
    int* __restrict__ ecol, int* __restrict__ rowptr,
    __half* __restrict__ agg16)
{
  __shared__ unsigned keysl[BCAP];
  __shared__ int hist[RANGE];
  __shared__ int sc[RANGE];
  __shared__ int segs[RANGE];
  __shared__ int sege[RANGE];
  int t = threadIdx.x, b = blockIdx.x;
  int s0 = bbase[b], e0 = bbase[b + 1];
  int cnt = e0 - s0;
  if (t < RANGE) hist[t] = 0;
  __syncthreads();
  for (int i = t; i < cnt; i += 512) {
    unsigned k = keys[s0 + i];
    if (i < BCAP) keysl[i] = k;
    atomicAdd(&hist[k & 255u], 1);
  }
  __syncthreads();
  int my = (t < RANGE) ? hist[t] : 0;
  if (t < RANGE) sc[t] = my;
  __syncthreads();
  for (int off = 1; off < RANGE; off <<= 1) {
    int v = 0;
    if (t < RANGE && t >= off) v = sc[t - off];
    __syncthreads();
    if (t < RANGE) sc[t] += v;
    __syncthreads();
  }
  if (t < RANGE) {
    int ex = sc[t] - my;
    int n = b * RANGE + t;
    if (n <= NN) rowptr[n] = s0 + ex;
    segs[t] = ex;
    sege[t] = sc[t];
    hist[t] = ex;                 // placement cursor
  }
  __syncthreads();
  for (int i = t; i < cnt; i += 512) {
    unsigned key = (i < BCAP) ? keysl[i] : keys[s0 + i];
    int rl = (int)(key & 255u);
    int idx = atomicAdd(&hist[rl], 1);
    ecol[s0 + idx] = (int)(key >> 8);
  }
  __syncthreads();   // ecol visible block-wide; segments in segs/sege

  const float2* nf2 = (const float2*)nf;
  for (int slot = t; slot < RANGE * 4; slot += 512) {
    int node = slot >> 2, q = slot & 3;
    int n = b * RANGE + node;
    if (n >= NN) continue;
    float w0[8], w1[8], bb[8];
#pragma unroll
    for (int j = 0; j < 8; ++j) {
      w0[j] = Win[q * 8 + j];
      w1[j] = Win[32 + q * 8 + j];
      bb[j] = bin[q * 8 + j];
    }
    int ss = segs[node], ee = sege[node];
    float acc[8];
#pragma unroll
    for (int j = 0; j < 8; ++j) acc[j] = 0.f;
    int i = ss;
    for (; i + 2 <= ee; i += 2) {
      int c0 = ecol[s0 + i], c1 = ecol[s0 + i + 1];   // L2-hot
      float2 f0 = nf2[c0];
      float2 f1 = nf2[c1];
#pragma unroll
      for (int j = 0; j < 8; ++j) {
        acc[j] += relu_(fmaf(f0.x, w0[j], fmaf(f0.y, w1[j], bb[j])));
        acc[j] += relu_(fmaf(f1.x, w0[j], fmaf(f1.y, w1[j], bb[j])));
      }
    }
    if (i < ee) {
      float2 f = nf2[ecol[s0 + i]];
#pragma unroll
      for (int j = 0; j < 8; ++j)
        acc[j] += relu_(fmaf(f.x, w0[j], fmaf(f.y, w1[j], bb[j])));
    }
    float dinv = 1.0f / fmaxf((float)(ee - ss), 1.0f);
    uint4 pk;
    __half2* pp = (__half2*)&pk;
#pragma unroll
    for (int k = 0; k < 4; ++k)
      pp[k] = __floats2half2_rn(acc[2*k] * dinv, acc[2*k+1] * dinv);
    ((uint4*)agg16)[(size_t)n * 4 + q] = pk;
  }
}

// layer-1 update: h16out = relu(concat(h16in, agg16) @ W + b)
__global__ __launch_bounds__(256) void k_update(
    const __half* __restrict__ h16in, const __half* __restrict__ agg16,
    const float* __restrict__ W, const float* __restrict__ b,
    __half* __restrict__ h16out)
{
  __shared__ float Ws[2048];
  __shared__ float bs[32];
  int t = threadIdx.x;
  for (int i = t; i < 2048; i += 256) Ws[i] = W[i];
  if (t < 32) bs[t] = b[t];
  __syncthreads();
  int n = blockIdx.x * 256 + t;
  if (n >= NN) return;

  float x[64];
  const uint4* hv = (const uint4*)(h16in + (size_t)n * 32);
  const uint4* av = (const uint4*)(agg16 + (size_t)n * 32);
#pragma unroll
  for (int j = 0; j < 4; ++j) {
    uint4 hx = hv[j], ax = av[j];
    const __half2* hp = (const __half2*)&hx;
    const __half2* ap = (const __half2*)&ax;
#pragma unroll
    for (int k = 0; k < 4; ++k) {
      float2 f = __half22float2(hp[k]);
      float2 g = __half22float2(ap[k]);
      x[j*8 + 2*k]      = f.x;
      x[j*8 + 2*k + 1]  = f.y;
      x[32 + j*8 + 2*k]     = g.x;
      x[32 + j*8 + 2*k + 1] = g.y;
    }
  }
  float acc[32];
#pragma unroll
  for (int j = 0; j < 32; ++j) acc[j] = bs[j];
#pragma unroll
  for (int k = 0; k < 64; ++k) {
    float xk = x[k];
    const float* wr = Ws + k * 32;
#pragma unroll
    for (int j = 0; j < 32; ++j) acc[j] = fmaf(xk, wr[j], acc[j]);
  }
  __half2* g2 = (__half2*)(h16out + (size_t)n * 32);
#pragma unroll
  for (int j = 0; j < 16; ++j)
    g2[j] = __floats2half2_rn(relu_(acc[2*j]), relu_(acc[2*j+1]));
}

// ---- fused layer-2: agg = mean gather(h16in[ecol]); h2 = relu([h16in,agg]@W+b);
//      u = h2@We1[0:32]+be1 ; v = h2@We1[32:64]   (64 nodes x 4 lanes / block)
__global__ __launch_bounds__(256) void k_agg_update2_uv(
    const int* __restrict__ rowptr, const int* __restrict__ ecol,
    const __half* __restrict__ h16in, const float* __restrict__ W,
    const float* __restrict__ b, const float* __restrict__ We1,
    const float* __restrict__ be1, __half* __restrict__ u,
    __half* __restrict__ v)
{
  __shared__ float Ws[2048];
  __shared__ float Es[2048];
  __shared__ float bs[32];
  __shared__ float bes[32];
  __shared__ float xs[64][65];
  int t = threadIdx.x;
  for (int i = t; i < 2048; i += 256) { Ws[i] = W[i]; Es[i] = We1[i]; }
  if (t < 32) { bs[t] = b[t]; bes[t] = be1[t]; }
  int q = t & 3, ln = t >> 2;
  int n = blockIdx.x * 64 + ln;
  bool act = (n < NN);
  const uint4* hv = (const uint4*)h16in;

  float acc[8];
#pragma unroll
  for (int j = 0; j < 8; ++j) acc[j] = 0.f;
  if (act) {
    int s = rowptr[n], e = rowptr[n + 1];
    int i = s;
    for (; i + 2 <= e; i += 2) {
      int c0 = ecol[i], c1 = ecol[i + 1];
      uint4 x0 = hv[c0 * 4 + q];
      uint4 x1 = hv[c1 * 4 + q];
      const __half2* p0 = (const __half2*)&x0;
      const __half2* p1 = (const __half2*)&x1;
#pragma unroll
      for (int k = 0; k < 4; ++k) {
        float2 f0 = __half22float2(p0[k]);
        float2 f1 = __half22float2(p1[k]);
        acc[2*k]   += f0.x + f1.x;
        acc[2*k+1] += f0.y + f1.y;
      }
    }
    if (i < e) {
      uint4 x = hv[ecol[i] * 4 + q];
      const __half2* hp = (const __half2*)&x;
#pragma unroll
      for (int k = 0; k < 4; ++k) {
        float2 f = __half22float2(hp[k]);
        acc[2*k] += f.x; acc[2*k+1] += f.y;
      }
    }
    float dinv = 1.0f / fmaxf((float)(e - s), 1.0f);
    uint4 hx = hv[n * 4 + q];
    const __half2* hp = (const __half2*)&hx;
#pragma unroll
    for (int k = 0; k < 4; ++k) {
      float2 f = __half22float2(hp[k]);
      xs[ln][q*8 + 2*k]     = f.x;
      xs[ln][q*8 + 2*k + 1] = f.y;
      xs[ln][32 + q*8 + 2*k]     = acc[2*k] * dinv;
      xs[ln][32 + q*8 + 2*k + 1] = acc[2*k+1] * dinv;
    }
  }
  __syncthreads();
  float h2[8];
#pragma unroll
  for (int j = 0; j < 8; ++j) h2[j] = bs[q*8 + j];
  if (act) {
    for (int k = 0; k < 64; ++k) {
      float xk = xs[ln][k];
      const float* wr = Ws + k * 32 + q * 8;
#pragma unroll
      for (int j = 0; j < 8; ++j) h2[j] = fmaf(xk, wr[j], h2[j]);
    }
#pragma unroll
    for (int j = 0; j < 8; ++j) h2[j] = relu_(h2[j]);
  }
  __syncthreads();           // all xs reads done
  if (act) {
#pragma unroll
    for (int j = 0; j < 8; ++j) xs[ln][q*8 + j] = h2[j];
  }
  __syncthreads();
  if (!act) return;
  float au[8], av[8];
#pragma unroll
  for (int j = 0; j < 8; ++j) { au[j] = bes[q*8 + j]; av[j] = 0.f; }
  for (int k = 0; k < 32; ++k) {
    float hk = xs[ln][k];
    const float* wu = Es + k * 32 + q * 8;
    const float* wv = Es + (32 + k) * 32 + q * 8;
#pragma unroll
    for (int j = 0; j < 8; ++j) {
      au[j] = fmaf(hk, wu[j], au[j]);
      av[j] = fmaf(hk, wv[j], av[j]);
    }
  }
  uint4 pu, pv;
  __half2* up = (__half2*)&pu;
  __half2* vp = (__half2*)&pv;
#pragma unroll
  for (int k = 0; k < 4; ++k) {
    up[k] = __floats2half2_rn(au[2*k], au[2*k+1]);
    vp[k] = __floats2half2_rn(av[2*k], av[2*k+1]);
  }
  ((uint4*)u)[n * 4 + q] = pu;
  ((uint4*)v)[n * 4 + q] = pv;
}

// flux[e] = relu(u[row]+v[col]).We2 + be2   (4 lanes/edge, uint4 fp16 loads)
__global__ __launch_bounds__(256) void k_flux(
    const int* __restrict__ row, const int* __restrict__ col,
    const __half* __restrict__ u, const __half* __restrict__ v,
    const float* __restrict__ We2, const float* __restrict__ be2,
    float* __restrict__ out)
{
  int gid = blockIdx.x * 256 + threadIdx.x;
  int e = gid >> 2, q = gid & 3;
  if (e >= NE) return;
  int r = row[e], c = col[e];
  uint4 ua = ((const uint4*)u)[r * 4 + q];   // 8 halfs
  uint4 vb = ((const uint4*)v)[c * 4 + q];
  const __half2* ah = (const __half2*)&ua;
  const __half2* bh = (const __half2*)&vb;
  const float4* w4 = (const float4*)(We2 + q * 8);
  float4 w0 = w4[0], w1 = w4[1];
  float p = 0.f;
  {
    float2 a = __half22float2(ah[0]), b = __half22float2(bh[0]);
    p += relu_(a.x + b.x) * w0.x + relu_(a.y + b.y) * w0.y;
    a = __half22float2(ah[1]); b = __half22float2(bh[1]);
    p += relu_(a.x + b.x) * w0.z + relu_(a.y + b.y) * w0.w;
    a = __half22float2(ah[2]); b = __half22float2(bh[2]);
    p += relu_(a.x + b.x) * w1.x + relu_(a.y + b.y) * w1.y;
    a = __half22float2(ah[3]); b = __half22float2(bh[3]);
    p += relu_(a.x + b.x) * w1.z + relu_(a.y + b.y) * w1.w;
  }
  p += __shfl_xor(p, 1, 4);
  p += __shfl_xor(p, 2, 4);
  if (q == 0) out[e] = p + be2[0];
}

extern "C" void kernel_launch(void* const* d_in, const int* in_sizes, int n_in,
                              void* d_out, int out_size, void* d_ws, size_t ws_size,
                              hipStream_t stream) {
  const float* nf   = (const float*)d_in[0];
  const int*   ei   = (const int*)d_in[1];
  const float* Win  = (const float*)d_in[2];
  const float* bin  = (const float*)d_in[3];
  const float* Wupd = (const float*)d_in[4];
  const float* bupd = (const float*)d_in[5];
  const float* We1  = (const float*)d_in[6];
  const float* be1  = (const float*)d_in[7];
  const float* We2  = (const float*)d_in[8];
  const float* be2  = (const float*)d_in[9];
  float* out = (float*)d_out;

  const int* row = ei;
  const int* col = ei + NE;

  char* ws = (char*)d_ws;
  const size_t HB16 = (size_t)NN * 32 * 2;            // 6.4 MB
  __half*       h16a  = (__half*)(ws);                // [0, 6.4)
  __half*       u     = (__half*)(ws);                // aliases h16a (dead after update1)
  __half*       h16b  = (__half*)(ws + HB16);         // [6.4, 12.8)
  unsigned int* keys  = (unsigned int*)(ws + 2 * HB16);           // 10 MB
  int*          ecol  = (int*)(ws + 2 * HB16 + 10000000);         // 10 MB
  __half*       agg16 = (__half*)(ws + 2 * HB16 + 20000000);      // 6.4 MB
  __half*       v     = (__half*)(ws + 2 * HB16 + 20000000 + HB16); // 6.4 MB
  char*         tail  = ws + 2 * HB16 + 20000000 + 2 * HB16;
  int*          rowptr    = (int*)(tail);                          // NN+1
  int*          btot      = (int*)(tail + 400512);
  int*          bbase     = (int*)(tail + 402560);
  int*          blockhist = (int*)(tail + 404608);                 // NBUCK*NBLK_A

  const int NB = (NN + 255) / 256;

  hipMemsetAsync(btot, 0, NBUCK * 4, stream);
  k_node_embed16<<<NB, 256, 0, stream>>>(nf, Win, bin, h16a);
  k_histA<<<NBLK_A, 512, 0, stream>>>(row, btot, blockhist);
  k_scanA<<<1, 512, 0, stream>>>(btot, bbase);
  k_colscan<<<NBUCK, 512, 0, stream>>>(blockhist, bbase);
  k_partition<<<NBLK_A, 512, 0, stream>>>(row, col, blockhist, keys);
  k_passB_agg1<<<NBUCK, 512, 0, stream>>>(bbase, keys, nf, Win, bin,
                                          ecol, rowptr, agg16);

  k_update<<<NB, 256, 0, stream>>>(h16a, agg16, Wupd, bupd, h16b);

  k_agg_update2_uv<<<(NN + 63) / 64, 256, 0, stream>>>(rowptr, ecol, h16b,
                                                       Wupd + 2048, bupd + 32,
                                                       We1, be1, u, v);

  k_flux<<<(NE * 4 + 255) / 256, 256, 0, stream>>>(row, col, u, v, We2, be2, out);
}

// Round 11
// 218.809 us; speedup vs baseline: 5.0334x; 1.0825x over previous
//
#include <hip/hip_runtime.h>
#include <hip/hip_fp16.h>

#define NN 100000
#define NE 2500000
#define RANGE 256
#define NBUCK 391                       // ceil(NN/256)
#define CHUNK 16384
#define NBLK_A ((NE + CHUNK - 1) / CHUNK)   // 153
#define BCAP 8192                       // passB LDS stage cap (mean 6400, sd ~80)

__device__ __forceinline__ float relu_(float x){ return fmaxf(x, 0.f); }

// ---- CSR build: counting sort, per-block histograms persisted ----

__global__ __launch_bounds__(512) void k_histA(const int* __restrict__ row,
                                               int* __restrict__ btot,
                                               int* __restrict__ blockhist)
{
  __shared__ int hist[NBUCK];
  int t = threadIdx.x;
  for (int i = t; i < NBUCK; i += 512) hist[i] = 0;
  __syncthreads();
  int e0 = blockIdx.x * CHUNK + t;
#pragma unroll
  for (int k = 0; k < CHUNK / 512; ++k) {
    int e = e0 + k * 512;
    if (e < NE) atomicAdd(&hist[row[e] >> 8], 1);
  }
  __syncthreads();
  for (int i = t; i < NBUCK; i += 512) {
    int c = hist[i];
    blockhist[(size_t)i * NBLK_A + blockIdx.x] = c;
    if (c) atomicAdd(&btot[i], c);
  }
}

__global__ __launch_bounds__(512) void k_scanA(const int* __restrict__ btot,
                                               int* __restrict__ bbase)
{
  __shared__ int s[512];
  int t = threadIdx.x;
  int my = (t < NBUCK) ? btot[t] : 0;
  s[t] = my;
  __syncthreads();
  for (int off = 1; off < 512; off <<= 1) {
    int v = (t >= off) ? s[t - off] : 0;
    __syncthreads();
    s[t] += v;
    __syncthreads();
  }
  if (t < NBUCK) bbase[t] = s[t] - my;
  if (t == 0) bbase[NBUCK] = NE;
}

__global__ __launch_bounds__(512) void k_colscan(int* __restrict__ blockhist,
                                                 const int* __restrict__ bbase)
{
  __shared__ int s[512];
  int i = blockIdx.x, t = threadIdx.x;
  int* rowp = blockhist + (size_t)i * NBLK_A;
  int my = (t < NBLK_A) ? rowp[t] : 0;
  s[t] = my;
  __syncthreads();
  for (int off = 1; off < 512; off <<= 1) {
    int v = (t >= off) ? s[t - off] : 0;
    __syncthreads();
    s[t] += v;
    __syncthreads();
  }
  if (t < NBLK_A) rowp[t] = bbase[i] + s[t] - my;
}

__global__ __launch_bounds__(512) void k_partition(
    const int* __restrict__ row, const int* __restrict__ col,
    const int* __restrict__ blockhist, unsigned int* __restrict__ keys)
{
  __shared__ int cur[NBUCK];
  __shared__ int base[NBUCK];
  int t = threadIdx.x, b = blockIdx.x;
  for (int i = t; i < NBUCK; i += 512) {
    base[i] = blockhist[(size_t)i * NBLK_A + b];
    cur[i] = 0;
  }
  __syncthreads();
  int e0 = b * CHUNK + t;
#pragma unroll
  for (int k = 0; k < CHUNK / 512; ++k) {
    int e = e0 + k * 512;
    if (e < NE) {
      int r = row[e];
      int bi = r >> 8;
      int idx = atomicAdd(&cur[bi], 1);
      keys[base[bi] + idx] = ((unsigned)col[e] << 8) | (unsigned)(r & 255);
    }
  }
}

// per-bucket: LDS-staged keys -> hist -> scan -> rowptr + ecol placement,
// then FUSED layer-1 agg (nf recompute) + layer-1 update GEMM -> h16b direct.
// x = [h1(n), agg(n)]; h1 recomputed in f32 from nf[n] (F=2).
__global__ __launch_bounds__(512) void k_passB_l1(
    const int* __restrict__ bbase, const unsigned int* __restrict__ keys,
    const float* __restrict__ nf, const float* __restrict__ Win,
    const float* __restrict__ bin, const float* __restrict__ W,
    const float* __restrict__ bupd,
    int* __restrict__ ecol, int* __restrict__ rowptr,
    __half* __restrict__ h16b)
{
  __shared__ unsigned keysl[BCAP];
  __shared__ int hist[RANGE];
  __shared__ int sc[RANGE];
  __shared__ int segs[RANGE];
  __shared__ int sege[RANGE];
  __shared__ float Ws[2048];
  __shared__ float bs[32];
  int t = threadIdx.x, b = blockIdx.x;
  for (int i = t; i < 2048; i += 512) Ws[i] = W[i];
  if (t < 32) bs[t] = bupd[t];
  int s0 = bbase[b], e0 = bbase[b + 1];
  int cnt = e0 - s0;
  if (t < RANGE) hist[t] = 0;
  __syncthreads();
  for (int i = t; i < cnt; i += 512) {
    unsigned k = keys[s0 + i];
    if (i < BCAP) keysl[i] = k;
    atomicAdd(&hist[k & 255u], 1);
  }
  __syncthreads();
  int my = (t < RANGE) ? hist[t] : 0;
  if (t < RANGE) sc[t] = my;
  __syncthreads();
  for (int off = 1; off < RANGE; off <<= 1) {
    int v = 0;
    if (t < RANGE && t >= off) v = sc[t - off];
    __syncthreads();
    if (t < RANGE) sc[t] += v;
    __syncthreads();
  }
  if (t < RANGE) {
    int ex = sc[t] - my;
    int n = b * RANGE + t;
    if (n <= NN) rowptr[n] = s0 + ex;
    segs[t] = ex;
    sege[t] = sc[t];
    hist[t] = ex;                 // placement cursor
  }
  __syncthreads();
  for (int i = t; i < cnt; i += 512) {
    unsigned key = (i < BCAP) ? keysl[i] : keys[s0 + i];
    int rl = (int)(key & 255u);
    int idx = atomicAdd(&hist[rl], 1);
    ecol[s0 + idx] = (int)(key >> 8);
  }
  __syncthreads();   // ecol visible block-wide; segments in segs/sege

  const float2* nf2 = (const float2*)nf;
  for (int slot = t; slot < RANGE * 4; slot += 512) {
    int node = slot >> 2, q = slot & 3;
    int n = b * RANGE + node;
    if (n >= NN) continue;       // whole 4-lane group shares n
    float w0[8], w1[8], bb[8];
#pragma unroll
    for (int j = 0; j < 8; ++j) {
      w0[j] = Win[q * 8 + j];
      w1[j] = Win[32 + q * 8 + j];
      bb[j] = bin[q * 8 + j];
    }
    int ss = segs[node], ee = sege[node];
    float acc[8];
#pragma unroll
    for (int j = 0; j < 8; ++j) acc[j] = 0.f;
    int i = ss;
    for (; i + 2 <= ee; i += 2) {
      int c0 = ecol[s0 + i], c1 = ecol[s0 + i + 1];   // L2-hot
      float2 f0 = nf2[c0];
      float2 f1 = nf2[c1];
#pragma unroll
      for (int j = 0; j < 8; ++j) {
        acc[j] += relu_(fmaf(f0.x, w0[j], fmaf(f0.y, w1[j], bb[j])));
        acc[j] += relu_(fmaf(f1.x, w0[j], fmaf(f1.y, w1[j], bb[j])));
      }
    }
    if (i < ee) {
      float2 f = nf2[ecol[s0 + i]];
#pragma unroll
      for (int j = 0; j < 8; ++j)
        acc[j] += relu_(fmaf(f.x, w0[j], fmaf(f.y, w1[j], bb[j])));
    }
    float dinv = 1.0f / fmaxf((float)(ee - ss), 1.0f);
    float g[8], a[8];
    float2 fn = nf2[n];
#pragma unroll
    for (int j = 0; j < 8; ++j) {
      g[j] = acc[j] * dinv;
      a[j] = relu_(fmaf(fn.x, w0[j], fmaf(fn.y, w1[j], bb[j])));
    }
    // 64x32 GEMM slice: o[j] = bs[q*8+j] + sum_k x[k]*W[k][q*8+j]
    float o[8];
#pragma unroll
    for (int j = 0; j < 8; ++j) o[j] = bs[q * 8 + j];
#pragma unroll
    for (int src = 0; src < 4; ++src) {
#pragma unroll
      for (int k = 0; k < 8; ++k) {
        float xh = __shfl(a[k], src, 4);
        float xg = __shfl(g[k], src, 4);
        const float* wr1 = Ws + (src * 8 + k) * 32 + q * 8;
        const float* wr2 = Ws + (32 + src * 8 + k) * 32 + q * 8;
#pragma unroll
        for (int j = 0; j < 8; ++j) {
          o[j] = fmaf(xh, wr1[j], o[j]);
          o[j] = fmaf(xg, wr2[j], o[j]);
        }
      }
    }
    uint4 pk;
    __half2* pp = (__half2*)&pk;
#pragma unroll
    for (int k = 0; k < 4; ++k)
      pp[k] = __floats2half2_rn(relu_(o[2*k]), relu_(o[2*k+1]));
    ((uint4*)h16b)[(size_t)n * 4 + q] = pk;
  }
}

// ---- fused layer-2: agg = mean gather(h16b[ecol]); h2 = relu([h16b,agg]@W+b);
//      u = h2@We1[0:32]+be1 ; v = h2@We1[32:64]   (64 nodes x 4 lanes / block)
__global__ __launch_bounds__(256) void k_agg_update2_uv(
    const int* __restrict__ rowptr, const int* __restrict__ ecol,
    const __half* __restrict__ h16in, const float* __restrict__ W,
    const float* __restrict__ b, const float* __restrict__ We1,
    const float* __restrict__ be1, __half* __restrict__ u,
    __half* __restrict__ v)
{
  __shared__ float Ws[2048];
  __shared__ float Es[2048];
  __shared__ float bs[32];
  __shared__ float bes[32];
  __shared__ float xs[64][65];
  int t = threadIdx.x;
  for (int i = t; i < 2048; i += 256) { Ws[i] = W[i]; Es[i] = We1[i]; }
  if (t < 32) { bs[t] = b[t]; bes[t] = be1[t]; }
  int q = t & 3, ln = t >> 2;
  int n = blockIdx.x * 64 + ln;
  bool act = (n < NN);
  const uint4* hv = (const uint4*)h16in;

  float acc[8];
#pragma unroll
  for (int j = 0; j < 8; ++j) acc[j] = 0.f;
  if (act) {
    int s = rowptr[n], e = rowptr[n + 1];
    int i = s;
    for (; i + 2 <= e; i += 2) {
      int c0 = ecol[i], c1 = ecol[i + 1];
      uint4 x0 = hv[c0 * 4 + q];
      uint4 x1 = hv[c1 * 4 + q];
      const __half2* p0 = (const __half2*)&x0;
      const __half2* p1 = (const __half2*)&x1;
#pragma unroll
      for (int k = 0; k < 4; ++k) {
        float2 f0 = __half22float2(p0[k]);
        float2 f1 = __half22float2(p1[k]);
        acc[2*k]   += f0.x + f1.x;
        acc[2*k+1] += f0.y + f1.y;
      }
    }
    if (i < e) {
      uint4 x = hv[ecol[i] * 4 + q];
      const __half2* hp = (const __half2*)&x;
#pragma unroll
      for (int k = 0; k < 4; ++k) {
        float2 f = __half22float2(hp[k]);
        acc[2*k] += f.x; acc[2*k+1] += f.y;
      }
    }
    float dinv = 1.0f / fmaxf((float)(e - s), 1.0f);
    uint4 hx = hv[n * 4 + q];
    const __half2* hp = (const __half2*)&hx;
#pragma unroll
    for (int k = 0; k < 4; ++k) {
      float2 f = __half22float2(hp[k]);
      xs[ln][q*8 + 2*k]     = f.x;
      xs[ln][q*8 + 2*k + 1] = f.y;
      xs[ln][32 + q*8 + 2*k]     = acc[2*k] * dinv;
      xs[ln][32 + q*8 + 2*k + 1] = acc[2*k+1] * dinv;
    }
  }
  __syncthreads();
  float h2[8];
#pragma unroll
  for (int j = 0; j < 8; ++j) h2[j] = bs[q*8 + j];
  if (act) {
    for (int k = 0; k < 64; ++k) {
      float xk = xs[ln][k];
      const float* wr = Ws + k * 32 + q * 8;
#pragma unroll
      for (int j = 0; j < 8; ++j) h2[j] = fmaf(xk, wr[j], h2[j]);
    }
#pragma unroll
    for (int j = 0; j < 8; ++j) h2[j] = relu_(h2[j]);
  }
  __syncthreads();           // all xs reads done
  if (act) {
#pragma unroll
    for (int j = 0; j < 8; ++j) xs[ln][q*8 + j] = h2[j];
  }
  __syncthreads();
  if (!act) return;
  float au[8], av[8];
#pragma unroll
  for (int j = 0; j < 8; ++j) { au[j] = bes[q*8 + j]; av[j] = 0.f; }
  for (int k = 0; k < 32; ++k) {
    float hk = xs[ln][k];
    const float* wu = Es + k * 32 + q * 8;
    const float* wv = Es + (32 + k) * 32 + q * 8;
#pragma unroll
    for (int j = 0; j < 8; ++j) {
      au[j] = fmaf(hk, wu[j], au[j]);
      av[j] = fmaf(hk, wv[j], av[j]);
    }
  }
  uint4 pu, pv;
  __half2* up = (__half2*)&pu;
  __half2* vp = (__half2*)&pv;
#pragma unroll
  for (int k = 0; k < 4; ++k) {
    up[k] = __floats2half2_rn(au[2*k], au[2*k+1]);
    vp[k] = __floats2half2_rn(av[2*k], av[2*k+1]);
  }
  ((uint4*)u)[n * 4 + q] = pu;
  ((uint4*)v)[n * 4 + q] = pv;
}

// flux[e] = relu(u[row]+v[col]).We2 + be2   (4 lanes/edge, uint4 fp16 loads)
__global__ __launch_bounds__(256) void k_flux(
    const int* __restrict__ row, const int* __restrict__ col,
    const __half* __restrict__ u, const __half* __restrict__ v,
    const float* __restrict__ We2, const float* __restrict__ be2,
    float* __restrict__ out)
{
  int gid = blockIdx.x * 256 + threadIdx.x;
  int e = gid >> 2, q = gid & 3;
  if (e >= NE) return;
  int r = row[e], c = col[e];
  uint4 ua = ((const uint4*)u)[r * 4 + q];   // 8 halfs
  uint4 vb = ((const uint4*)v)[c * 4 + q];
  const __half2* ah = (const __half2*)&ua;
  const __half2* bh = (const __half2*)&vb;
  const float4* w4 = (const float4*)(We2 + q * 8);
  float4 w0 = w4[0], w1 = w4[1];
  float p = 0.f;
  {
    float2 a = __half22float2(ah[0]), b = __half22float2(bh[0]);
    p += relu_(a.x + b.x) * w0.x + relu_(a.y + b.y) * w0.y;
    a = __half22float2(ah[1]); b = __half22float2(bh[1]);
    p += relu_(a.x + b.x) * w0.z + relu_(a.y + b.y) * w0.w;
    a = __half22float2(ah[2]); b = __half22float2(bh[2]);
    p += relu_(a.x + b.x) * w1.x + relu_(a.y + b.y) * w1.y;
    a = __half22float2(ah[3]); b = __half22float2(bh[3]);
    p += relu_(a.x + b.x) * w1.z + relu_(a.y + b.y) * w1.w;
  }
  p += __shfl_xor(p, 1, 4);
  p += __shfl_xor(p, 2, 4);
  if (q == 0) out[e] = p + be2[0];
}

extern "C" void kernel_launch(void* const* d_in, const int* in_sizes, int n_in,
                              void* d_out, int out_size, void* d_ws, size_t ws_size,
                              hipStream_t stream) {
  const float* nf   = (const float*)d_in[0];
  const int*   ei   = (const int*)d_in[1];
  const float* Win  = (const float*)d_in[2];
  const float* bin  = (const float*)d_in[3];
  const float* Wupd = (const float*)d_in[4];
  const float* bupd = (const float*)d_in[5];
  const float* We1  = (const float*)d_in[6];
  const float* be1  = (const float*)d_in[7];
  const float* We2  = (const float*)d_in[8];
  const float* be2  = (const float*)d_in[9];
  float* out = (float*)d_out;

  const int* row = ei;
  const int* col = ei + NE;

  char* ws = (char*)d_ws;
  const size_t HB16 = (size_t)NN * 32 * 2;            // 6.4 MB
  unsigned int* keys = (unsigned int*)(ws);                       // 10 MB
  int*          ecol = (int*)(ws + 10000000);                     // 10 MB
  __half*       h16b = (__half*)(ws + 20000000);                  // 6.4 MB
  __half*       u    = (__half*)(ws + 20000000 + HB16);           // 6.4 MB
  __half*       v    = (__half*)(ws + 20000000 + 2 * HB16);       // 6.4 MB
  char*         tail = ws + 20000000 + 3 * HB16;
  int*          rowptr    = (int*)(tail);                          // NN+1
  int*          btot      = (int*)(tail + 400512);
  int*          bbase     = (int*)(tail + 402560);
  int*          blockhist = (int*)(tail + 404608);                 // NBUCK*NBLK_A

  hipMemsetAsync(btot, 0, NBUCK * 4, stream);
  k_histA<<<NBLK_A, 512, 0, stream>>>(row, btot, blockhist);
  k_scanA<<<1, 512, 0, stream>>>(btot, bbase);
  k_colscan<<<NBUCK, 512, 0, stream>>>(blockhist, bbase);
  k_partition<<<NBLK_A, 512, 0, stream>>>(row, col, blockhist, keys);
  k_passB_l1<<<NBUCK, 512, 0, stream>>>(bbase, keys, nf, Win, bin,
                                        Wupd, bupd, ecol, rowptr, h16b);

  k_agg_update2_uv<<<(NN + 63) / 64, 256, 0, stream>>>(rowptr, ecol, h16b,
                                                       Wupd + 2048, bupd + 32,
                                                       We1, be1, u, v);

  k_flux<<<(NE * 4 + 255) / 256, 256, 0, stream>>>(row, col, u, v, We2, be2, out);
}

// Round 12
// 210.920 us; speedup vs baseline: 5.2217x; 1.0374x over previous
//
#include <hip/hip_runtime.h>
#include <hip/hip_fp16.h>

#define NN 100000
#define NE 2500000
#define RANGE 256
#define NBUCK 391                       // ceil(NN/256)
#define CAP 8192                        // fixed bucket capacity (mean 6400, sd ~80)
#define CHUNK 16384
#define NBLK_A ((NE + CHUNK - 1) / CHUNK)   // 153
#define BCAP 8192                       // passB LDS stage cap

__device__ __forceinline__ float relu_(float x){ return fmaxf(x, 0.f); }

// ---- single-pass partition: per-block LDS histogram -> atomic bucket
//      reservation -> write packed keys (col<<8)|(row&255) into fixed-cap buckets
__global__ __launch_bounds__(512) void k_partition1(
    const int* __restrict__ row, const int* __restrict__ col,
    int* __restrict__ cursor, unsigned int* __restrict__ keys)
{
  __shared__ int hist[NBUCK];
  __shared__ int base[NBUCK];
  int t = threadIdx.x, b = blockIdx.x;
  for (int i = t; i < NBUCK; i += 512) hist[i] = 0;
  __syncthreads();
  int e0 = b * CHUNK + t;
#pragma unroll
  for (int k = 0; k < CHUNK / 512; ++k) {
    int e = e0 + k * 512;
    if (e < NE) atomicAdd(&hist[row[e] >> 8], 1);
  }
  __syncthreads();
  for (int i = t; i < NBUCK; i += 512) {
    int c = hist[i];
    base[i] = c ? (i * CAP + atomicAdd(&cursor[i], c)) : 0;
    hist[i] = 0;
  }
  __syncthreads();
#pragma unroll
  for (int k = 0; k < CHUNK / 512; ++k) {
    int e = e0 + k * 512;
    if (e < NE) {
      int r = row[e];
      int bi = r >> 8;
      int idx = atomicAdd(&hist[bi], 1);
      keys[base[bi] + idx] = ((unsigned)col[e] << 8) | (unsigned)(r & 255);
    }
  }
}

// per-bucket: LDS-staged keys -> hist -> scan -> rowseg + ecol placement,
// then FUSED layer-1 agg (nf recompute) + layer-1 update GEMM -> h16b direct.
__global__ __launch_bounds__(512) void k_passB_l1(
    const int* __restrict__ cursor, const unsigned int* __restrict__ keys,
    const float* __restrict__ nf, const float* __restrict__ Win,
    const float* __restrict__ bin, const float* __restrict__ W,
    const float* __restrict__ bupd,
    int* __restrict__ ecol, int2* __restrict__ rowseg,
    __half* __restrict__ h16b)
{
  __shared__ unsigned keysl[BCAP];
  __shared__ int hist[RANGE];
  __shared__ int sc[RANGE];
  __shared__ int segs[RANGE];
  __shared__ int sege[RANGE];
  __shared__ float Ws[2048];
  __shared__ float bs[32];
  int t = threadIdx.x, b = blockIdx.x;
  for (int i = t; i < 2048; i += 512) Ws[i] = W[i];
  if (t < 32) bs[t] = bupd[t];
  int s0 = b * CAP;
  int cnt = cursor[b];
  if (t < RANGE) hist[t] = 0;
  __syncthreads();
  for (int i = t; i < cnt; i += 512) {
    unsigned k = keys[s0 + i];
    if (i < BCAP) keysl[i] = k;
    atomicAdd(&hist[k & 255u], 1);
  }
  __syncthreads();
  int my = (t < RANGE) ? hist[t] : 0;
  if (t < RANGE) sc[t] = my;
  __syncthreads();
  for (int off = 1; off < RANGE; off <<= 1) {
    int v = 0;
    if (t < RANGE && t >= off) v = sc[t - off];
    __syncthreads();
    if (t < RANGE) sc[t] += v;
    __syncthreads();
  }
  if (t < RANGE) {
    int ex = sc[t] - my;
    int n = b * RANGE + t;
    if (n < NN) rowseg[n] = make_int2(s0 + ex, s0 + sc[t]);
    segs[t] = ex;
    sege[t] = sc[t];
    hist[t] = ex;                 // placement cursor
  }
  __syncthreads();
  for (int i = t; i < cnt; i += 512) {
    unsigned key = (i < BCAP) ? keysl[i] : keys[s0 + i];
    int rl = (int)(key & 255u);
    int idx = atomicAdd(&hist[rl], 1);
    ecol[s0 + idx] = (int)(key >> 8);
  }
  __syncthreads();   // ecol visible block-wide; segments in segs/sege

  const float2* nf2 = (const float2*)nf;
  for (int slot = t; slot < RANGE * 4; slot += 512) {
    int node = slot >> 2, q = slot & 3;
    int n = b * RANGE + node;
    if (n >= NN) continue;       // whole 4-lane group shares n
    float w0[8], w1[8], bb[8];
#pragma unroll
    for (int j = 0; j < 8; ++j) {
      w0[j] = Win[q * 8 + j];
      w1[j] = Win[32 + q * 8 + j];
      bb[j] = bin[q * 8 + j];
    }
    int ss = segs[node], ee = sege[node];
    float acc[8];
#pragma unroll
    for (int j = 0; j < 8; ++j) acc[j] = 0.f;
    int i = ss;
    for (; i + 2 <= ee; i += 2) {
      int c0 = ecol[s0 + i], c1 = ecol[s0 + i + 1];   // L2-hot
      float2 f0 = nf2[c0];
      float2 f1 = nf2[c1];
#pragma unroll
      for (int j = 0; j < 8; ++j) {
        acc[j] += relu_(fmaf(f0.x, w0[j], fmaf(f0.y, w1[j], bb[j])));
        acc[j] += relu_(fmaf(f1.x, w0[j], fmaf(f1.y, w1[j], bb[j])));
      }
    }
    if (i < ee) {
      float2 f = nf2[ecol[s0 + i]];
#pragma unroll
      for (int j = 0; j < 8; ++j)
        acc[j] += relu_(fmaf(f.x, w0[j], fmaf(f.y, w1[j], bb[j])));
    }
    float dinv = 1.0f / fmaxf((float)(ee - ss), 1.0f);
    float g[8], a[8];
    float2 fn = nf2[n];
#pragma unroll
    for (int j = 0; j < 8; ++j) {
      g[j] = acc[j] * dinv;
      a[j] = relu_(fmaf(fn.x, w0[j], fmaf(fn.y, w1[j], bb[j])));
    }
    // 64x32 GEMM slice via 4-lane shfl exchange
    float o[8];
#pragma unroll
    for (int j = 0; j < 8; ++j) o[j] = bs[q * 8 + j];
#pragma unroll
    for (int src = 0; src < 4; ++src) {
#pragma unroll
      for (int k = 0; k < 8; ++k) {
        float xh = __shfl(a[k], src, 4);
        float xg = __shfl(g[k], src, 4);
        const float* wr1 = Ws + (src * 8 + k) * 32 + q * 8;
        const float* wr2 = Ws + (32 + src * 8 + k) * 32 + q * 8;
#pragma unroll
        for (int j = 0; j < 8; ++j) {
          o[j] = fmaf(xh, wr1[j], o[j]);
          o[j] = fmaf(xg, wr2[j], o[j]);
        }
      }
    }
    uint4 pk;
    __half2* pp = (__half2*)&pk;
#pragma unroll
    for (int k = 0; k < 4; ++k)
      pp[k] = __floats2half2_rn(relu_(o[2*k]), relu_(o[2*k+1]));
    ((uint4*)h16b)[(size_t)n * 4 + q] = pk;
  }
}

// ---- fused layer-2, register-exchange version (no xs LDS -> full occupancy):
// agg = mean gather(h16b[ecol]); h2 = relu([h16b,agg]@W+b);
// u = h2@We1[0:32]+be1 ; v = h2@We1[32:64]   (64 nodes x 4 lanes / block)
__global__ __launch_bounds__(256) void k_agg_update2_uv(
    const int2* __restrict__ rowseg, const int* __restrict__ ecol,
    const __half* __restrict__ h16in, const float* __restrict__ W,
    const float* __restrict__ b, const float* __restrict__ We1,
    const float* __restrict__ be1, __half* __restrict__ u,
    __half* __restrict__ v)
{
  __shared__ float Ws[2048];
  __shared__ float Es[2048];
  __shared__ float bs[32];
  __shared__ float bes[32];
  int t = threadIdx.x;
  for (int i = t; i < 2048; i += 256) { Ws[i] = W[i]; Es[i] = We1[i]; }
  if (t < 32) { bs[t] = b[t]; bes[t] = be1[t]; }
  __syncthreads();
  int q = t & 3, ln = t >> 2;
  int n = blockIdx.x * 64 + ln;
  if (n >= NN) return;          // group-uniform exit; shfl stays intra-group
  const uint4* hv = (const uint4*)h16in;

  int2 seg = rowseg[n];
  float acc[8];
#pragma unroll
  for (int j = 0; j < 8; ++j) acc[j] = 0.f;
  int i = seg.x;
  for (; i + 2 <= seg.y; i += 2) {
    int c0 = ecol[i], c1 = ecol[i + 1];
    uint4 x0 = hv[c0 * 4 + q];
    uint4 x1 = hv[c1 * 4 + q];
    const __half2* p0 = (const __half2*)&x0;
    const __half2* p1 = (const __half2*)&x1;
#pragma unroll
    for (int k = 0; k < 4; ++k) {
      float2 f0 = __half22float2(p0[k]);
      float2 f1 = __half22float2(p1[k]);
      acc[2*k]   += f0.x + f1.x;
      acc[2*k+1] += f0.y + f1.y;
    }
  }
  if (i < seg.y) {
    uint4 x = hv[ecol[i] * 4 + q];
    const __half2* hp = (const __half2*)&x;
#pragma unroll
    for (int k = 0; k < 4; ++k) {
      float2 f = __half22float2(hp[k]);
      acc[2*k] += f.x; acc[2*k+1] += f.y;
    }
  }
  float dinv = 1.0f / fmaxf((float)(seg.y - seg.x), 1.0f);
  float a[8], g[8];
  {
    uint4 hx = hv[n * 4 + q];
    const __half2* hp = (const __half2*)&hx;
#pragma unroll
    for (int k = 0; k < 4; ++k) {
      float2 f = __half22float2(hp[k]);
      a[2*k] = f.x; a[2*k+1] = f.y;
      g[2*k] = acc[2*k] * dinv; g[2*k+1] = acc[2*k+1] * dinv;
    }
  }
  // GEMM1: h2 = relu([a|g] @ W + b), 4-lane shfl exchange
  float h2[8];
#pragma unroll
  for (int j = 0; j < 8; ++j) h2[j] = bs[q*8 + j];
#pragma unroll
  for (int src = 0; src < 4; ++src) {
#pragma unroll
    for (int k = 0; k < 8; ++k) {
      float xh = __shfl(a[k], src, 4);
      float xg = __shfl(g[k], src, 4);
      const float* wr1 = Ws + (src * 8 + k) * 32 + q * 8;
      const float* wr2 = Ws + (32 + src * 8 + k) * 32 + q * 8;
#pragma unroll
      for (int j = 0; j < 8; ++j) {
        h2[j] = fmaf(xh, wr1[j], h2[j]);
        h2[j] = fmaf(xg, wr2[j], h2[j]);
      }
    }
  }
#pragma unroll
  for (int j = 0; j < 8; ++j) h2[j] = relu_(h2[j]);
  // GEMM2: u = h2@Es[0:32]+be1 ; v = h2@Es[32:64]
  float au[8], av[8];
#pragma unroll
  for (int j = 0; j < 8; ++j) { au[j] = bes[q*8 + j]; av[j] = 0.f; }
#pragma unroll
  for (int src = 0; src < 4; ++src) {
#pragma unroll
    for (int k = 0; k < 8; ++k) {
      float xk = __shfl(h2[k], src, 4);
      const float* wu = Es + (src * 8 + k) * 32 + q * 8;
      const float* wv = Es + (32 + src * 8 + k) * 32 + q * 8;
#pragma unroll
      for (int j = 0; j < 8; ++j) {
        au[j] = fmaf(xk, wu[j], au[j]);
        av[j] = fmaf(xk, wv[j], av[j]);
      }
    }
  }
  uint4 pu, pv;
  __half2* up = (__half2*)&pu;
  __half2* vp = (__half2*)&pv;
#pragma unroll
  for (int k = 0; k < 4; ++k) {
    up[k] = __floats2half2_rn(au[2*k], au[2*k+1]);
    vp[k] = __floats2half2_rn(av[2*k], av[2*k+1]);
  }
  ((uint4*)u)[n * 4 + q] = pu;
  ((uint4*)v)[n * 4 + q] = pv;
}

// flux[e] = relu(u[row]+v[col]).We2 + be2   (4 lanes/edge, uint4 fp16 loads)
__global__ __launch_bounds__(256) void k_flux(
    const int* __restrict__ row, const int* __restrict__ col,
    const __half* __restrict__ u, const __half* __restrict__ v,
    const float* __restrict__ We2, const float* __restrict__ be2,
    float* __restrict__ out)
{
  int gid = blockIdx.x * 256 + threadIdx.x;
  int e = gid >> 2, q = gid & 3;
  if (e >= NE) return;
  int r = row[e], c = col[e];
  uint4 ua = ((const uint4*)u)[r * 4 + q];   // 8 halfs
  uint4 vb = ((const uint4*)v)[c * 4 + q];
  const __half2* ah = (const __half2*)&ua;
  const __half2* bh = (const __half2*)&vb;
  const float4* w4 = (const float4*)(We2 + q * 8);
  float4 w0 = w4[0], w1 = w4[1];
  float p = 0.f;
  {
    float2 a = __half22float2(ah[0]), b = __half22float2(bh[0]);
    p += relu_(a.x + b.x) * w0.x + relu_(a.y + b.y) * w0.y;
    a = __half22float2(ah[1]); b = __half22float2(bh[1]);
    p += relu_(a.x + b.x) * w0.z + relu_(a.y + b.y) * w0.w;
    a = __half22float2(ah[2]); b = __half22float2(bh[2]);
    p += relu_(a.x + b.x) * w1.x + relu_(a.y + b.y) * w1.y;
    a = __half22float2(ah[3]); b = __half22float2(bh[3]);
    p += relu_(a.x + b.x) * w1.z + relu_(a.y + b.y) * w1.w;
  }
  p += __shfl_xor(p, 1, 4);
  p += __shfl_xor(p, 2, 4);
  if (q == 0) out[e] = p + be2[0];
}

extern "C" void kernel_launch(void* const* d_in, const int* in_sizes, int n_in,
                              void* d_out, int out_size, void* d_ws, size_t ws_size,
                              hipStream_t stream) {
  const float* nf   = (const float*)d_in[0];
  const int*   ei   = (const int*)d_in[1];
  const float* Win  = (const float*)d_in[2];
  const float* bin  = (const float*)d_in[3];
  const float* Wupd = (const float*)d_in[4];
  const float* bupd = (const float*)d_in[5];
  const float* We1  = (const float*)d_in[6];
  const float* be1  = (const float*)d_in[7];
  const float* We2  = (const float*)d_in[8];
  const float* be2  = (const float*)d_in[9];
  float* out = (float*)d_out;

  const int* row = ei;
  const int* col = ei + NE;

  char* ws = (char*)d_ws;
  const size_t KB = (size_t)NBUCK * CAP * 4;          // 12.81 MB
  const size_t HB16 = (size_t)NN * 32 * 2;            // 6.4 MB
  unsigned int* keys   = (unsigned int*)(ws);                    // 12.81 MB
  int*          ecol   = (int*)(ws + KB);                        // 12.81 MB
  __half*       h16b   = (__half*)(ws + 2 * KB);                 // 6.4 MB
  __half*       u      = (__half*)(ws + 2 * KB + HB16);          // 6.4 MB
  __half*       v      = (__half*)(ws + 2 * KB + 2 * HB16);      // 6.4 MB
  int2*         rowseg = (int2*)(ws + 2 * KB + 3 * HB16);        // 800 KB
  int*          cursor = (int*)(ws + 2 * KB + 3 * HB16 + 800000);// NBUCK ints

  hipMemsetAsync(cursor, 0, NBUCK * 4, stream);
  k_partition1<<<NBLK_A, 512, 0, stream>>>(row, col, cursor, keys);
  k_passB_l1<<<NBUCK, 512, 0, stream>>>(cursor, keys, nf, Win, bin,
                                        Wupd, bupd, ecol, rowseg, h16b);
  k_agg_update2_uv<<<(NN + 63) / 64, 256, 0, stream>>>(rowseg, ecol, h16b,
                                                       Wupd + 2048, bupd + 32,
                                                       We1, be1, u, v);
  k_flux<<<(NE * 4 + 255) / 256, 256, 0, stream>>>(row, col, u, v, We2, be2, out);
}